// Round 1
// baseline (387.210 us; speedup 1.0000x reference)
//
#include <hip/hip_runtime.h>
#include <math.h>

namespace {
constexpr int BB = 2048;
constexpr int SS = 512;
constexpr int KK = SS - 1;   // 511
constexpr int NSQ = 4;       // fixed squarings; balanced norm <= 10.5 < 16
constexpr float SCV = 0.0625f; // 2^-NSQ

// 1/n! for n=0..14
__device__ __constant__ float INVF[15] = {
    1.0f, 1.0f, 0.5f, 1.66666672e-1f, 4.16666679e-2f, 8.33333377e-3f,
    1.38888892e-3f, 1.98412701e-4f, 2.48015876e-5f, 2.75573195e-6f,
    2.75573188e-7f, 2.50521084e-8f, 2.08767563e-9f, 1.60590438e-10f,
    1.14707456e-11f};
}

__global__ __launch_bounds__(256) void pbw_kernel(
    const float* __restrict__ it_eff,
    const float* __restrict__ ts,
    const float* __restrict__ p_tin_prod,
    const float* __restrict__ p_tmil_raw,
    const float* __restrict__ p_aamp_raw,
    const float* __restrict__ p_aloop_raw,
    const float* __restrict__ p_tout_raw,
    const float* __restrict__ p_tsf_raw,
    const float* __restrict__ p_tdiff_raw,
    float* __restrict__ out)
{
    // LDS: coefficients (5 float4 per k), u values, y values
    __shared__ float4 sc[KK * 5];   // 40880 B
    __shared__ float  su[SS];       //  2048 B
    __shared__ float  sy[SS];       //  2048 B

    const int b = blockIdx.x;
    const int t = threadIdx.x;

    // derived scalar params (wave-uniform; scalar-unit cheap)
    const float tin_prod  = p_tin_prod[0];
    const float tmil_prod = log1pf(expf(p_tmil_raw[0]));
    const float Aamp1     = 1.0f / log1pf(expf(p_aamp_raw[0])) + 1.0f;
    const float Aloop1    = 1.0f / log1pf(expf(p_aloop_raw[0])) + 1.0f;
    const float tau_out   = log1pf(expf(p_tout_raw[0]));
    const float wsf       = 1.0f / log1pf(expf(p_tsf_raw[0]));
    const float wdf       = 1.0f / log1pf(expf(p_tdiff_raw[0]));

    const float* rowI = it_eff + (size_t)b * SS;
    const float* rowT = ts     + (size_t)b * SS;

    // u = log(it_eff) into LDS
    for (int j = t; j < SS; j += 256) su[j] = logf(rowI[j]);

    // ---- Phase 1: per-k discretization (Ad, Bd, Bt) via structured expm ----
    for (int k = t; k < KK; k += 256) {
        const float I  = rowI[k + 1];
        const float dt = rowT[k + 1] - rowT[k];

        const float tin = tin_prod  / I;
        const float tml = tmil_prod / I;
        const float idn = 1.0f / ((tin + tml) * tau_out);
        const float a   = (tin + tau_out + Aamp1 * tml) * idn;
        const float w2  = Aloop1 * idn;
        const float w   = sqrtf(w2);
        const float iw  = 1.0f / w;

        // balanced (D=diag(w,1,1,1)) continuous matrix * dt, pre-scaled by 2^-4
        const float dts = dt * SCV;
        const float f00 = -a * dts;
        const float f01 = -w * dts;
        const float f10 =  w * dts;     // also g0 (balanced input vector, scaled)
        const float f21 =  wsf * dts;
        const float f22 = -f21;
        const float f32 =  wdf * dts;
        const float f33 = -f32;
        const float g0  =  f10;

        // E = exp(Fs) via degree-12 Taylor (Horner), structured:
        // blocks: T2=[t00 t01; t10 t11], TC=[c00 c01; c10 c11], TL=[l00 0; l10 l11]
        float t00 = fmaf(f00, 1.0f/12.0f, 1.0f), t01 = f01 * (1.0f/12.0f);
        float t10 = f10 * (1.0f/12.0f),          t11 = 1.0f;
        float c00 = 0.0f, c01 = f21 * (1.0f/12.0f), c10 = 0.0f, c11 = 0.0f;
        float l00 = fmaf(f22, 1.0f/12.0f, 1.0f);
        float l10 = f32 * (1.0f/12.0f);
        float l11 = fmaf(f33, 1.0f/12.0f, 1.0f);
#pragma unroll
        for (int m = 11; m >= 1; --m) {
            const float rm = 1.0f / (float)m;  // folds under unroll
            const float p00 = f00*t00 + f01*t10;
            const float p01 = f00*t01 + f01*t11;
            const float p10 = f10*t00;
            const float p11 = f10*t01;
            const float q00 = f21*t10 + f22*c00;
            const float q01 = f21*t11 + f22*c01;
            const float q10 = f32*c00 + f33*c10;
            const float q11 = f32*c01 + f33*c11;
            const float m00 = f22*l00;
            const float m10 = f32*l00 + f33*l10;
            const float m11 = f33*l11;
            t00 = fmaf(p00, rm, 1.0f); t01 = p01*rm;
            t10 = p10*rm;              t11 = fmaf(p11, rm, 1.0f);
            c00 = q00*rm; c01 = q01*rm; c10 = q10*rm; c11 = q11*rm;
            l00 = fmaf(m00, rm, 1.0f); l10 = m10*rm; l11 = fmaf(m11, rm, 1.0f);
        }

        // G1 = phi1(Fs) gs ; G2 = phi2(Fs) gs * 2^-NSQ   (Krylov-style series)
        float p0 = g0, p1 = 0.0f, p2 = 0.0f, p3 = 0.0f;
        float g10 = 0, g11 = 0, g12 = 0, g13 = 0;
        float g20 = 0, g21 = 0, g22 = 0, g23 = 0;
#pragma unroll
        for (int n = 0; n <= 12; ++n) {
            const float c1 = INVF[n + 1], c2 = INVF[n + 2];
            g10 = fmaf(p0, c1, g10); g11 = fmaf(p1, c1, g11);
            g12 = fmaf(p2, c1, g12); g13 = fmaf(p3, c1, g13);
            g20 = fmaf(p0, c2, g20); g21 = fmaf(p1, c2, g21);
            g22 = fmaf(p2, c2, g22); g23 = fmaf(p3, c2, g23);
            const float np0 = f00*p0 + f01*p1;
            const float np1 = f10*p0;
            const float np2 = f21*p1 + f22*p2;
            const float np3 = f32*p2 + f33*p3;
            p0 = np0; p1 = np1; p2 = np2; p3 = np3;
        }
        g20 *= SCV; g21 *= SCV; g22 *= SCV; g23 *= SCV;
        float h = SCV;

        // NSQ squarings with exact phi-doubling recurrences
#pragma unroll
        for (int i = 0; i < NSQ; ++i) {
            const float e2v0 = t00*g20 + t01*g21;
            const float e2v1 = t10*g20 + t11*g21;
            const float e2v2 = c00*g20 + c01*g21 + l00*g22;
            const float e2v3 = c10*g20 + c11*g21 + l10*g22 + l11*g23;
            const float e1v0 = t00*g10 + t01*g11;
            const float e1v1 = t10*g10 + t11*g11;
            const float e1v2 = c00*g10 + c01*g11 + l00*g12;
            const float e1v3 = c10*g10 + c11*g11 + l10*g12 + l11*g13;
            g20 = e2v0 + h*g10 + g20; g21 = e2v1 + h*g11 + g21;
            g22 = e2v2 + h*g12 + g22; g23 = e2v3 + h*g13 + g23;
            g10 = e1v0 + g10; g11 = e1v1 + g11;
            g12 = e1v2 + g12; g13 = e1v3 + g13;
            h += h;
            const float p00 = t00*t00 + t01*t10;
            const float p01 = t00*t01 + t01*t11;
            const float p10 = t10*t00 + t11*t10;
            const float p11 = t10*t01 + t11*t11;
            const float q00 = c00*t00 + c01*t10 + l00*c00;
            const float q01 = c00*t01 + c01*t11 + l00*c01;
            const float q10 = c10*t00 + c11*t10 + l10*c00 + l11*c10;
            const float q11 = c10*t01 + c11*t11 + l10*c01 + l11*c11;
            const float m00 = l00*l00;
            const float m10 = l10*l00 + l11*l10;
            const float m11 = l11*l11;
            t00 = p00; t01 = p01; t10 = p10; t11 = p11;
            c00 = q00; c01 = q01; c10 = q10; c11 = q11;
            l00 = m00; l10 = m10; l11 = m11;
        }

        // unbalance: Ad = D E D^-1 ; G *= D
        const float a00 = t00,      a01 = w * t01;
        const float a10 = t10 * iw, a11 = t11;
        const float a20 = c00 * iw, a21 = c01, a22 = l00;
        const float a30 = c10 * iw, a31 = c11, a32 = l10, a33 = l11;
        g10 *= w; g20 *= w;
        const float bd0 = g10 - g20, bd1 = g11 - g21;
        const float bd2 = g12 - g22, bd3 = g13 - g23;

        sc[5*k + 0] = make_float4(a00, a01, a10, a11);
        sc[5*k + 1] = make_float4(a20, a21, a22, a30);
        sc[5*k + 2] = make_float4(a31, a32, a33, bd0);
        sc[5*k + 3] = make_float4(bd1, bd2, bd3, g20);
        sc[5*k + 4] = make_float4(g21, g22, g23, 0.0f);
    }

    __syncthreads();

    // ---- Phase 2: sequential scan (single lane; coefs are x-independent) ----
    if (t == 0) {
        float x0 = 0.0f, x1 = su[0], x2 = x1, x3 = x1;
        sy[0] = x1;
        for (int k = 0; k < KK; ++k) {
            const float4 q0 = sc[5*k + 0];
            const float4 q1 = sc[5*k + 1];
            const float4 q2 = sc[5*k + 2];
            const float4 q3 = sc[5*k + 3];
            const float4 q4 = sc[5*k + 4];
            const float uk  = su[k];
            const float uk1 = su[k + 1];
            const float n0 = q0.x*x0 + q0.y*x1 + q2.w*uk + q3.w*uk1;
            const float n1 = q0.z*x0 + q0.w*x1 + q3.x*uk + q4.x*uk1;
            const float n2 = q1.x*x0 + q1.y*x1 + q1.z*x2 + q3.y*uk + q4.y*uk1;
            const float n3 = q1.w*x0 + q2.x*x1 + q2.y*x2 + q2.z*x3
                           + q3.z*uk + q4.z*uk1;
            x0 = n0; x1 = n1; x2 = n2; x3 = n3;
            sy[k + 1] = n3;
        }
    }

    __syncthreads();

    // coalesced output
    const int base = b * SS;
    out[base + t]       = sy[t];
    out[base + 256 + t] = sy[256 + t];
}

extern "C" void kernel_launch(void* const* d_in, const int* in_sizes, int n_in,
                              void* d_out, int out_size, void* d_ws, size_t ws_size,
                              hipStream_t stream) {
    const float* it_eff = (const float*)d_in[0];
    const float* ts     = (const float*)d_in[1];
    const float* p2 = (const float*)d_in[2];
    const float* p3 = (const float*)d_in[3];
    const float* p4 = (const float*)d_in[4];
    const float* p5 = (const float*)d_in[5];
    const float* p6 = (const float*)d_in[6];
    const float* p7 = (const float*)d_in[7];
    const float* p8 = (const float*)d_in[8];
    float* out = (float*)d_out;

    pbw_kernel<<<dim3(BB), dim3(256), 0, stream>>>(
        it_eff, ts, p2, p3, p4, p5, p6, p7, p8, out);
}

// Round 2
// 108.686 us; speedup vs baseline: 3.5626x; 3.5626x over previous
//
#include <hip/hip_runtime.h>
#include <math.h>

namespace {
constexpr int BB = 2048;
constexpr int SS = 512;
constexpr int NSQ = 4;        // fixed squarings; balanced norm <= ~10.5 < 16
constexpr float SCV = 0.0625f;

// 1/n! for n=0..14
__device__ __constant__ float INVF[15] = {
    1.0f, 1.0f, 0.5f, 1.66666672e-1f, 4.16666679e-2f, 8.33333377e-3f,
    1.38888892e-3f, 1.98412701e-4f, 2.48015876e-5f, 2.75573195e-6f,
    2.75573188e-7f, 2.50521084e-8f, 2.08767563e-9f, 1.60590438e-10f,
    1.14707456e-11f};
}

// affine map x -> A x + c, A block-lower-triangular with 11 nonzeros
struct Aff {
    float a00, a01, a10, a11;          // 2x2 oscillator block
    float a20, a21, a22;               // row 2
    float a30, a31, a32, a33;          // row 3
    float c0, c1, c2, c3;              // input vector
};

__device__ __forceinline__ Aff aff_identity() {
    Aff r;
    r.a00 = 1.f; r.a01 = 0.f; r.a10 = 0.f; r.a11 = 1.f;
    r.a20 = 0.f; r.a21 = 0.f; r.a22 = 1.f;
    r.a30 = 0.f; r.a31 = 0.f; r.a32 = 0.f; r.a33 = 1.f;
    r.c0 = 0.f; r.c1 = 0.f; r.c2 = 0.f; r.c3 = 0.f;
    return r;
}

// r = s o f  (apply f first, then s); structure closed, ~42 FMA
__device__ __forceinline__ Aff aff_compose(const Aff& s, const Aff& f) {
    Aff r;
    r.a00 = s.a00*f.a00 + s.a01*f.a10;
    r.a01 = s.a00*f.a01 + s.a01*f.a11;
    r.a10 = s.a10*f.a00 + s.a11*f.a10;
    r.a11 = s.a10*f.a01 + s.a11*f.a11;
    r.a20 = s.a20*f.a00 + s.a21*f.a10 + s.a22*f.a20;
    r.a21 = s.a20*f.a01 + s.a21*f.a11 + s.a22*f.a21;
    r.a22 = s.a22*f.a22;
    r.a30 = s.a30*f.a00 + s.a31*f.a10 + s.a32*f.a20 + s.a33*f.a30;
    r.a31 = s.a30*f.a01 + s.a31*f.a11 + s.a32*f.a21 + s.a33*f.a31;
    r.a32 = s.a32*f.a22 + s.a33*f.a32;
    r.a33 = s.a33*f.a33;
    r.c0 = s.a00*f.c0 + s.a01*f.c1 + s.c0;
    r.c1 = s.a10*f.c0 + s.a11*f.c1 + s.c1;
    r.c2 = s.a20*f.c0 + s.a21*f.c1 + s.a22*f.c2 + s.c2;
    r.c3 = s.a30*f.c0 + s.a31*f.c1 + s.a32*f.c2 + s.a33*f.c3 + s.c3;
    return r;
}

__device__ __forceinline__ Aff aff_shfl_up(const Aff& a, int d) {
    Aff r;
    r.a00 = __shfl_up(a.a00, d, 64); r.a01 = __shfl_up(a.a01, d, 64);
    r.a10 = __shfl_up(a.a10, d, 64); r.a11 = __shfl_up(a.a11, d, 64);
    r.a20 = __shfl_up(a.a20, d, 64); r.a21 = __shfl_up(a.a21, d, 64);
    r.a22 = __shfl_up(a.a22, d, 64);
    r.a30 = __shfl_up(a.a30, d, 64); r.a31 = __shfl_up(a.a31, d, 64);
    r.a32 = __shfl_up(a.a32, d, 64); r.a33 = __shfl_up(a.a33, d, 64);
    r.c0 = __shfl_up(a.c0, d, 64); r.c1 = __shfl_up(a.c1, d, 64);
    r.c2 = __shfl_up(a.c2, d, 64); r.c3 = __shfl_up(a.c3, d, 64);
    return r;
}

// branchless: keep p if ok, else identity
__device__ __forceinline__ Aff aff_sel_ident(const Aff& p, bool ok) {
    Aff r;
    r.a00 = ok ? p.a00 : 1.f; r.a01 = ok ? p.a01 : 0.f;
    r.a10 = ok ? p.a10 : 0.f; r.a11 = ok ? p.a11 : 1.f;
    r.a20 = ok ? p.a20 : 0.f; r.a21 = ok ? p.a21 : 0.f;
    r.a22 = ok ? p.a22 : 1.f;
    r.a30 = ok ? p.a30 : 0.f; r.a31 = ok ? p.a31 : 0.f;
    r.a32 = ok ? p.a32 : 0.f; r.a33 = ok ? p.a33 : 1.f;
    r.c0 = ok ? p.c0 : 0.f; r.c1 = ok ? p.c1 : 0.f;
    r.c2 = ok ? p.c2 : 0.f; r.c3 = ok ? p.c3 : 0.f;
    return r;
}

// x <- A x + c
__device__ __forceinline__ void aff_apply(const Aff& m, float& x0, float& x1,
                                          float& x2, float& x3) {
    const float y0 = m.a00*x0 + m.a01*x1 + m.c0;
    const float y1 = m.a10*x0 + m.a11*x1 + m.c1;
    const float y2 = m.a20*x0 + m.a21*x1 + m.a22*x2 + m.c2;
    const float y3 = m.a30*x0 + m.a31*x1 + m.a32*x2 + m.a33*x3 + m.c3;
    x0 = y0; x1 = y1; x2 = y2; x3 = y3;
}

__global__ __launch_bounds__(256) void pbw_kernel(
    const float* __restrict__ it_eff,
    const float* __restrict__ ts,
    const float* __restrict__ p_tin_prod,
    const float* __restrict__ p_tmil_raw,
    const float* __restrict__ p_aamp_raw,
    const float* __restrict__ p_aloop_raw,
    const float* __restrict__ p_tout_raw,
    const float* __restrict__ p_tsf_raw,
    const float* __restrict__ p_tdiff_raw,
    float* __restrict__ out)
{
    // word-major coefficient store: sc[w*512 + k], w=0..14
    // w: 0..10 = A nonzeros (a00,a01,a10,a11,a20,a21,a22,a30,a31,a32,a33)
    //    11..14 = c (Bd*u_k + Bt*u_{k+1})
    __shared__ float sc[15 * SS];   // 30720 B
    __shared__ float su[SS];        //  2048 B
    __shared__ float sy[SS];        //  2048 B
    __shared__ float swc[4 * 15];   //   240 B  (per-wave composites)

    const int b = blockIdx.x;
    const int t = threadIdx.x;
    const int lane = t & 63;
    const int wv = t >> 6;

    const float tin_prod  = p_tin_prod[0];
    const float tmil_prod = log1pf(expf(p_tmil_raw[0]));
    const float Aamp1     = 1.0f / log1pf(expf(p_aamp_raw[0])) + 1.0f;
    const float Aloop1    = 1.0f / log1pf(expf(p_aloop_raw[0])) + 1.0f;
    const float tau_out   = log1pf(expf(p_tout_raw[0]));
    const float wsf       = 1.0f / log1pf(expf(p_tsf_raw[0]));
    const float wdf       = 1.0f / log1pf(expf(p_tdiff_raw[0]));

    const float* rowI = it_eff + (size_t)b * SS;
    const float* rowT = ts     + (size_t)b * SS;

    // u = log(it_eff)
    for (int j = t; j < SS; j += 256) su[j] = logf(rowI[j]);
    __syncthreads();

    // ---- Phase 1: structured expm -> (A_k, c_k) for k = 0..510; identity at 511
    for (int k = t; k < SS; k += 256) {
        if (k == SS - 1) {
            sc[0*SS+k] = 1.f; sc[1*SS+k] = 0.f; sc[2*SS+k] = 0.f; sc[3*SS+k] = 1.f;
            sc[4*SS+k] = 0.f; sc[5*SS+k] = 0.f; sc[6*SS+k] = 1.f;
            sc[7*SS+k] = 0.f; sc[8*SS+k] = 0.f; sc[9*SS+k] = 0.f; sc[10*SS+k] = 1.f;
            sc[11*SS+k] = 0.f; sc[12*SS+k] = 0.f; sc[13*SS+k] = 0.f; sc[14*SS+k] = 0.f;
            continue;
        }
        const float I  = rowI[k + 1];
        const float dt = rowT[k + 1] - rowT[k];

        const float tin = tin_prod  / I;
        const float tml = tmil_prod / I;
        const float idn = 1.0f / ((tin + tml) * tau_out);
        const float a   = (tin + tau_out + Aamp1 * tml) * idn;
        const float w2  = Aloop1 * idn;
        const float w   = sqrtf(w2);
        const float iw  = 1.0f / w;

        const float dts = dt * SCV;
        const float f00 = -a * dts;
        const float f01 = -w * dts;
        const float f10 =  w * dts;
        const float f21 =  wsf * dts;
        const float f22 = -f21;
        const float f32 =  wdf * dts;
        const float f33 = -f32;
        const float g0  =  f10;

        // E = exp(Fs), degree-12 Taylor (Horner), structured blocks
        float t00 = fmaf(f00, 1.0f/12.0f, 1.0f), t01 = f01 * (1.0f/12.0f);
        float t10 = f10 * (1.0f/12.0f),          t11 = 1.0f;
        float c00 = 0.0f, c01 = f21 * (1.0f/12.0f), c10 = 0.0f, c11 = 0.0f;
        float l00 = fmaf(f22, 1.0f/12.0f, 1.0f);
        float l10 = f32 * (1.0f/12.0f);
        float l11 = fmaf(f33, 1.0f/12.0f, 1.0f);
#pragma unroll
        for (int m = 11; m >= 1; --m) {
            const float rm = 1.0f / (float)m;
            const float p00 = f00*t00 + f01*t10;
            const float p01 = f00*t01 + f01*t11;
            const float p10 = f10*t00;
            const float p11 = f10*t01;
            const float q00 = f21*t10 + f22*c00;
            const float q01 = f21*t11 + f22*c01;
            const float q10 = f32*c00 + f33*c10;
            const float q11 = f32*c01 + f33*c11;
            const float m00 = f22*l00;
            const float m10 = f32*l00 + f33*l10;
            const float m11 = f33*l11;
            t00 = fmaf(p00, rm, 1.0f); t01 = p01*rm;
            t10 = p10*rm;              t11 = fmaf(p11, rm, 1.0f);
            c00 = q00*rm; c01 = q01*rm; c10 = q10*rm; c11 = q11*rm;
            l00 = fmaf(m00, rm, 1.0f); l10 = m10*rm; l11 = fmaf(m11, rm, 1.0f);
        }

        // phi1, phi2 applied to gs
        float p0 = g0, p1 = 0.0f, p2 = 0.0f, p3 = 0.0f;
        float g10 = 0, g11 = 0, g12 = 0, g13 = 0;
        float g20 = 0, g21 = 0, g22 = 0, g23 = 0;
#pragma unroll
        for (int n = 0; n <= 12; ++n) {
            const float c1 = INVF[n + 1], c2 = INVF[n + 2];
            g10 = fmaf(p0, c1, g10); g11 = fmaf(p1, c1, g11);
            g12 = fmaf(p2, c1, g12); g13 = fmaf(p3, c1, g13);
            g20 = fmaf(p0, c2, g20); g21 = fmaf(p1, c2, g21);
            g22 = fmaf(p2, c2, g22); g23 = fmaf(p3, c2, g23);
            const float np0 = f00*p0 + f01*p1;
            const float np1 = f10*p0;
            const float np2 = f21*p1 + f22*p2;
            const float np3 = f32*p2 + f33*p3;
            p0 = np0; p1 = np1; p2 = np2; p3 = np3;
        }
        g20 *= SCV; g21 *= SCV; g22 *= SCV; g23 *= SCV;
        float h = SCV;

#pragma unroll
        for (int i = 0; i < NSQ; ++i) {
            const float e2v0 = t00*g20 + t01*g21;
            const float e2v1 = t10*g20 + t11*g21;
            const float e2v2 = c00*g20 + c01*g21 + l00*g22;
            const float e2v3 = c10*g20 + c11*g21 + l10*g22 + l11*g23;
            const float e1v0 = t00*g10 + t01*g11;
            const float e1v1 = t10*g10 + t11*g11;
            const float e1v2 = c00*g10 + c01*g11 + l00*g12;
            const float e1v3 = c10*g10 + c11*g11 + l10*g12 + l11*g13;
            g20 = e2v0 + h*g10 + g20; g21 = e2v1 + h*g11 + g21;
            g22 = e2v2 + h*g12 + g22; g23 = e2v3 + h*g13 + g23;
            g10 = e1v0 + g10; g11 = e1v1 + g11;
            g12 = e1v2 + g12; g13 = e1v3 + g13;
            h += h;
            const float p00 = t00*t00 + t01*t10;
            const float p01 = t00*t01 + t01*t11;
            const float p10 = t10*t00 + t11*t10;
            const float p11 = t10*t01 + t11*t11;
            const float q00 = c00*t00 + c01*t10 + l00*c00;
            const float q01 = c00*t01 + c01*t11 + l00*c01;
            const float q10 = c10*t00 + c11*t10 + l10*c00 + l11*c10;
            const float q11 = c10*t01 + c11*t11 + l10*c01 + l11*c11;
            const float m00 = l00*l00;
            const float m10 = l10*l00 + l11*l10;
            const float m11 = l11*l11;
            t00 = p00; t01 = p01; t10 = p10; t11 = p11;
            c00 = q00; c01 = q01; c10 = q10; c11 = q11;
            l00 = m00; l10 = m10; l11 = m11;
        }

        // unbalance
        const float a00 = t00,      a01 = w * t01;
        const float a10 = t10 * iw, a11 = t11;
        const float a20 = c00 * iw, a21 = c01, a22 = l00;
        const float a30 = c10 * iw, a31 = c11, a32 = l10, a33 = l11;
        g10 *= w; g20 *= w;
        const float bd0 = g10 - g20, bd1 = g11 - g21;
        const float bd2 = g12 - g22, bd3 = g13 - g23;

        const float uk  = su[k];
        const float uk1 = su[k + 1];

        sc[ 0*SS+k] = a00; sc[ 1*SS+k] = a01; sc[ 2*SS+k] = a10; sc[ 3*SS+k] = a11;
        sc[ 4*SS+k] = a20; sc[ 5*SS+k] = a21; sc[ 6*SS+k] = a22;
        sc[ 7*SS+k] = a30; sc[ 8*SS+k] = a31; sc[ 9*SS+k] = a32; sc[10*SS+k] = a33;
        sc[11*SS+k] = fmaf(bd0, uk, g20 * uk1);
        sc[12*SS+k] = fmaf(bd1, uk, g21 * uk1);
        sc[13*SS+k] = fmaf(bd2, uk, g22 * uk1);
        sc[14*SS+k] = fmaf(bd3, uk, g23 * uk1);
    }

    __syncthreads();

    // ---- Phase 2: parallel affine scan, 2 steps per thread ----
    const int k0 = 2 * t;
    float v1[15], v2[15];
#pragma unroll
    for (int w = 0; w < 15; ++w) {
        const float2 vv = *(const float2*)&sc[w * SS + k0];
        v1[w] = vv.x; v2[w] = vv.y;
    }
    Aff m1, m2;
    m1.a00=v1[0]; m1.a01=v1[1]; m1.a10=v1[2]; m1.a11=v1[3];
    m1.a20=v1[4]; m1.a21=v1[5]; m1.a22=v1[6];
    m1.a30=v1[7]; m1.a31=v1[8]; m1.a32=v1[9]; m1.a33=v1[10];
    m1.c0=v1[11]; m1.c1=v1[12]; m1.c2=v1[13]; m1.c3=v1[14];
    m2.a00=v2[0]; m2.a01=v2[1]; m2.a10=v2[2]; m2.a11=v2[3];
    m2.a20=v2[4]; m2.a21=v2[5]; m2.a22=v2[6];
    m2.a30=v2[7]; m2.a31=v2[8]; m2.a32=v2[9]; m2.a33=v2[10];
    m2.c0=v2[11]; m2.c1=v2[12]; m2.c2=v2[13]; m2.c3=v2[14];

    Aff cur = aff_compose(m2, m1);

    // intra-wave Kogge-Stone inclusive scan over 64 lanes
#pragma unroll
    for (int d = 1; d < 64; d <<= 1) {
        Aff p = aff_shfl_up(cur, d);
        p = aff_sel_ident(p, lane >= d);
        cur = aff_compose(cur, p);
    }

    if (lane == 63) {
        float* dst = &swc[wv * 15];
        dst[0]=cur.a00; dst[1]=cur.a01; dst[2]=cur.a10; dst[3]=cur.a11;
        dst[4]=cur.a20; dst[5]=cur.a21; dst[6]=cur.a22;
        dst[7]=cur.a30; dst[8]=cur.a31; dst[9]=cur.a32; dst[10]=cur.a33;
        dst[11]=cur.c0; dst[12]=cur.c1; dst[13]=cur.c2; dst[14]=cur.c3;
    }
    __syncthreads();

    // wave-start state: apply preceding wave composites to x0
    const float u0 = su[0];
    float x0 = 0.0f, x1 = u0, x2 = u0, x3 = u0;
    for (int j = 0; j < wv; ++j) {
        const float* m = &swc[j * 15];
        Aff wm;
        wm.a00=m[0]; wm.a01=m[1]; wm.a10=m[2]; wm.a11=m[3];
        wm.a20=m[4]; wm.a21=m[5]; wm.a22=m[6];
        wm.a30=m[7]; wm.a31=m[8]; wm.a32=m[9]; wm.a33=m[10];
        wm.c0=m[11]; wm.c1=m[12]; wm.c2=m[13]; wm.c3=m[14];
        aff_apply(wm, x0, x1, x2, x3);
    }

    // exclusive intra-wave prefix -> thread-start state
    Aff ex = aff_shfl_up(cur, 1);
    ex = aff_sel_ident(ex, lane >= 1);
    aff_apply(ex, x0, x1, x2, x3);

    // replay the 2 local steps
    aff_apply(m1, x0, x1, x2, x3);
    sy[k0 + 1] = x3;
    aff_apply(m2, x0, x1, x2, x3);
    if (k0 + 2 < SS) sy[k0 + 2] = x3;
    if (t == 0) sy[0] = u0;

    __syncthreads();

    const int base = b * SS;
    out[base + t]       = sy[t];
    out[base + 256 + t] = sy[256 + t];
}

extern "C" void kernel_launch(void* const* d_in, const int* in_sizes, int n_in,
                              void* d_out, int out_size, void* d_ws, size_t ws_size,
                              hipStream_t stream) {
    const float* it_eff = (const float*)d_in[0];
    const float* ts     = (const float*)d_in[1];
    const float* p2 = (const float*)d_in[2];
    const float* p3 = (const float*)d_in[3];
    const float* p4 = (const float*)d_in[4];
    const float* p5 = (const float*)d_in[5];
    const float* p6 = (const float*)d_in[6];
    const float* p7 = (const float*)d_in[7];
    const float* p8 = (const float*)d_in[8];
    float* out = (float*)d_out;

    pbw_kernel<<<dim3(BB), dim3(256), 0, stream>>>(
        it_eff, ts, p2, p3, p4, p5, p6, p7, p8, out);
}

// Round 3
// 103.099 us; speedup vs baseline: 3.7557x; 1.0542x over previous
//
#include <hip/hip_runtime.h>
#include <math.h>

namespace {
constexpr int BB = 2048;
constexpr int SS = 512;
constexpr int NSQ = 4;         // balanced norm <= 10.5; /16 -> theta <= 0.66
constexpr float SCV = 0.0625f; // 2^-NSQ
}

// fast 1-ulp hardware ops (tolerance is 6e-2; these are ~1e-7 rel)
__device__ __forceinline__ float frcp(float x) { return __builtin_amdgcn_rcpf(x); }
__device__ __forceinline__ float frsq(float x) { return __builtin_amdgcn_rsqf(x); }
__device__ __forceinline__ float flog(float x) {
    return __builtin_amdgcn_logf(x) * 0.69314718056f;
}

// affine map x -> A x + c, A block-lower-triangular with 11 nonzeros
struct Aff {
    float a00, a01, a10, a11;   // 2x2 oscillator block
    float a20, a21, a22;        // row 2
    float a30, a31, a32, a33;   // row 3
    float c0, c1, c2, c3;       // input vector
};

__device__ __forceinline__ Aff aff_identity() {
    Aff r;
    r.a00 = 1.f; r.a01 = 0.f; r.a10 = 0.f; r.a11 = 1.f;
    r.a20 = 0.f; r.a21 = 0.f; r.a22 = 1.f;
    r.a30 = 0.f; r.a31 = 0.f; r.a32 = 0.f; r.a33 = 1.f;
    r.c0 = 0.f; r.c1 = 0.f; r.c2 = 0.f; r.c3 = 0.f;
    return r;
}

// r = s o f  (apply f first, then s); structure closed, ~42 FMA
__device__ __forceinline__ Aff aff_compose(const Aff& s, const Aff& f) {
    Aff r;
    r.a00 = s.a00*f.a00 + s.a01*f.a10;
    r.a01 = s.a00*f.a01 + s.a01*f.a11;
    r.a10 = s.a10*f.a00 + s.a11*f.a10;
    r.a11 = s.a10*f.a01 + s.a11*f.a11;
    r.a20 = s.a20*f.a00 + s.a21*f.a10 + s.a22*f.a20;
    r.a21 = s.a20*f.a01 + s.a21*f.a11 + s.a22*f.a21;
    r.a22 = s.a22*f.a22;
    r.a30 = s.a30*f.a00 + s.a31*f.a10 + s.a32*f.a20 + s.a33*f.a30;
    r.a31 = s.a30*f.a01 + s.a31*f.a11 + s.a32*f.a21 + s.a33*f.a31;
    r.a32 = s.a32*f.a22 + s.a33*f.a32;
    r.a33 = s.a33*f.a33;
    r.c0 = s.a00*f.c0 + s.a01*f.c1 + s.c0;
    r.c1 = s.a10*f.c0 + s.a11*f.c1 + s.c1;
    r.c2 = s.a20*f.c0 + s.a21*f.c1 + s.a22*f.c2 + s.c2;
    r.c3 = s.a30*f.c0 + s.a31*f.c1 + s.a32*f.c2 + s.a33*f.c3 + s.c3;
    return r;
}

__device__ __forceinline__ Aff aff_shfl_up(const Aff& a, int d) {
    Aff r;
    r.a00 = __shfl_up(a.a00, d, 64); r.a01 = __shfl_up(a.a01, d, 64);
    r.a10 = __shfl_up(a.a10, d, 64); r.a11 = __shfl_up(a.a11, d, 64);
    r.a20 = __shfl_up(a.a20, d, 64); r.a21 = __shfl_up(a.a21, d, 64);
    r.a22 = __shfl_up(a.a22, d, 64);
    r.a30 = __shfl_up(a.a30, d, 64); r.a31 = __shfl_up(a.a31, d, 64);
    r.a32 = __shfl_up(a.a32, d, 64); r.a33 = __shfl_up(a.a33, d, 64);
    r.c0 = __shfl_up(a.c0, d, 64); r.c1 = __shfl_up(a.c1, d, 64);
    r.c2 = __shfl_up(a.c2, d, 64); r.c3 = __shfl_up(a.c3, d, 64);
    return r;
}

// branchless: keep p if ok, else identity
__device__ __forceinline__ Aff aff_sel_ident(const Aff& p, bool ok) {
    Aff r;
    r.a00 = ok ? p.a00 : 1.f; r.a01 = ok ? p.a01 : 0.f;
    r.a10 = ok ? p.a10 : 0.f; r.a11 = ok ? p.a11 : 1.f;
    r.a20 = ok ? p.a20 : 0.f; r.a21 = ok ? p.a21 : 0.f;
    r.a22 = ok ? p.a22 : 1.f;
    r.a30 = ok ? p.a30 : 0.f; r.a31 = ok ? p.a31 : 0.f;
    r.a32 = ok ? p.a32 : 0.f; r.a33 = ok ? p.a33 : 1.f;
    r.c0 = ok ? p.c0 : 0.f; r.c1 = ok ? p.c1 : 0.f;
    r.c2 = ok ? p.c2 : 0.f; r.c3 = ok ? p.c3 : 0.f;
    return r;
}

// x <- A x + c
__device__ __forceinline__ void aff_apply(const Aff& m, float& x0, float& x1,
                                          float& x2, float& x3) {
    const float y0 = m.a00*x0 + m.a01*x1 + m.c0;
    const float y1 = m.a10*x0 + m.a11*x1 + m.c1;
    const float y2 = m.a20*x0 + m.a21*x1 + m.a22*x2 + m.c2;
    const float y3 = m.a30*x0 + m.a31*x1 + m.a32*x2 + m.a33*x3 + m.c3;
    x0 = y0; x1 = y1; x2 = y2; x3 = y3;
}

// one discretization step: structured expm (balanced, scale-&-square) + phi1/phi2
__device__ __forceinline__ Aff make_step(
    float Iss, float dt, float uk, float uk1,
    float sprod, float aprod, float tau_out, float Aloop1,
    float wsf, float wdf)
{
    const float rI  = frcp(Iss);
    const float s   = sprod * rI;                 // tin + tml
    const float idn = frcp(s * tau_out);
    const float a   = fmaf(aprod, rI, tau_out) * idn;
    const float w2  = Aloop1 * idn;
    const float iw  = frsq(w2);
    const float w   = w2 * iw;

    const float dts = dt * SCV;
    const float f00 = -a * dts;
    const float f01 = -w * dts;
    const float f10 =  w * dts;
    const float f21 =  wsf * dts;
    const float f22 = -f21;
    const float f32 =  wdf * dts;
    const float f33 = -f32;
    const float g0  =  f10;

    // E = exp(Fs), degree-6 Taylor (Horner); theta<=0.66 -> err ~1e-5
    float t00 = fmaf(f00, 1.0f/6.0f, 1.0f), t01 = f01 * (1.0f/6.0f);
    float t10 = f10 * (1.0f/6.0f),          t11 = 1.0f;
    float c00 = 0.0f, c01 = f21 * (1.0f/6.0f), c10 = 0.0f, c11 = 0.0f;
    float l00 = fmaf(f22, 1.0f/6.0f, 1.0f);
    float l10 = f32 * (1.0f/6.0f);
    float l11 = fmaf(f33, 1.0f/6.0f, 1.0f);
#pragma unroll
    for (int m = 5; m >= 1; --m) {
        const float rm = 1.0f / (float)m;  // folds to literal under unroll
        const float p00 = f00*t00 + f01*t10;
        const float p01 = f00*t01 + f01*t11;
        const float p10 = f10*t00;
        const float p11 = f10*t01;
        const float q00 = f21*t10 + f22*c00;
        const float q01 = f21*t11 + f22*c01;
        const float q10 = f32*c00 + f33*c10;
        const float q11 = f32*c01 + f33*c11;
        const float m00 = f22*l00;
        const float m10 = f32*l00 + f33*l10;
        const float m11 = f33*l11;
        t00 = fmaf(p00, rm, 1.0f); t01 = p01*rm;
        t10 = p10*rm;              t11 = fmaf(p11, rm, 1.0f);
        c00 = q00*rm; c01 = q01*rm; c10 = q10*rm; c11 = q11*rm;
        l00 = fmaf(m00, rm, 1.0f); l10 = m10*rm; l11 = fmaf(m11, rm, 1.0f);
    }

    // phi1, phi2 applied to gs: 7 terms (n=0..6), remainder ~1e-6
    constexpr float INV[9] = {1.0f, 1.0f, 0.5f, 1.6666667e-1f, 4.1666668e-2f,
                              8.3333338e-3f, 1.3888889e-3f, 1.9841270e-4f,
                              2.4801588e-5f};
    float p0 = g0, p1 = 0.0f, p2 = 0.0f, p3 = 0.0f;
    float g10 = 0, g11 = 0, g12 = 0, g13 = 0;
    float g20 = 0, g21 = 0, g22 = 0, g23 = 0;
#pragma unroll
    for (int n = 0; n <= 6; ++n) {
        const float c1 = INV[n + 1], c2 = INV[n + 2];
        g10 = fmaf(p0, c1, g10); g11 = fmaf(p1, c1, g11);
        g12 = fmaf(p2, c1, g12); g13 = fmaf(p3, c1, g13);
        g20 = fmaf(p0, c2, g20); g21 = fmaf(p1, c2, g21);
        g22 = fmaf(p2, c2, g22); g23 = fmaf(p3, c2, g23);
        const float np0 = f00*p0 + f01*p1;
        const float np1 = f10*p0;
        const float np2 = f21*p1 + f22*p2;
        const float np3 = f32*p2 + f33*p3;
        p0 = np0; p1 = np1; p2 = np2; p3 = np3;
    }
    g20 *= SCV; g21 *= SCV; g22 *= SCV; g23 *= SCV;
    float h = SCV;

    // NSQ squarings with exact phi-doubling recurrences
#pragma unroll
    for (int i = 0; i < NSQ; ++i) {
        const float e2v0 = t00*g20 + t01*g21;
        const float e2v1 = t10*g20 + t11*g21;
        const float e2v2 = c00*g20 + c01*g21 + l00*g22;
        const float e2v3 = c10*g20 + c11*g21 + l10*g22 + l11*g23;
        const float e1v0 = t00*g10 + t01*g11;
        const float e1v1 = t10*g10 + t11*g11;
        const float e1v2 = c00*g10 + c01*g11 + l00*g12;
        const float e1v3 = c10*g10 + c11*g11 + l10*g12 + l11*g13;
        g20 = e2v0 + h*g10 + g20; g21 = e2v1 + h*g11 + g21;
        g22 = e2v2 + h*g12 + g22; g23 = e2v3 + h*g13 + g23;
        g10 = e1v0 + g10; g11 = e1v1 + g11;
        g12 = e1v2 + g12; g13 = e1v3 + g13;
        h += h;
        const float p00 = t00*t00 + t01*t10;
        const float p01 = t00*t01 + t01*t11;
        const float p10 = t10*t00 + t11*t10;
        const float p11 = t10*t01 + t11*t11;
        const float q00 = c00*t00 + c01*t10 + l00*c00;
        const float q01 = c00*t01 + c01*t11 + l00*c01;
        const float q10 = c10*t00 + c11*t10 + l10*c00 + l11*c10;
        const float q11 = c10*t01 + c11*t11 + l10*c01 + l11*c11;
        const float m00 = l00*l00;
        const float m10 = l10*l00 + l11*l10;
        const float m11 = l11*l11;
        t00 = p00; t01 = p01; t10 = p10; t11 = p11;
        c00 = q00; c01 = q01; c10 = q10; c11 = q11;
        l00 = m00; l10 = m10; l11 = m11;
    }

    // unbalance: Ad = D E D^-1, D = diag(w,1,1,1); G *= D
    Aff r;
    r.a00 = t00;      r.a01 = w * t01;
    r.a10 = t10 * iw; r.a11 = t11;
    r.a20 = c00 * iw; r.a21 = c01; r.a22 = l00;
    r.a30 = c10 * iw; r.a31 = c11; r.a32 = l10; r.a33 = l11;
    g10 *= w; g20 *= w;
    // c = G1*uk + G2*(uk1-uk)   (== Bd*uk + Bt*uk1)
    const float du = uk1 - uk;
    r.c0 = fmaf(g10, uk, g20 * du);
    r.c1 = fmaf(g11, uk, g21 * du);
    r.c2 = fmaf(g12, uk, g22 * du);
    r.c3 = fmaf(g13, uk, g23 * du);
    return r;
}

__global__ __launch_bounds__(256) void pbw_kernel(
    const float* __restrict__ it_eff,
    const float* __restrict__ ts,
    const float* __restrict__ p_tin_prod,
    const float* __restrict__ p_tmil_raw,
    const float* __restrict__ p_aamp_raw,
    const float* __restrict__ p_aloop_raw,
    const float* __restrict__ p_tout_raw,
    const float* __restrict__ p_tsf_raw,
    const float* __restrict__ p_tdiff_raw,
    float* __restrict__ out)
{
    __shared__ float swc[4 * 15];   // per-wave composites
    __shared__ float sy[SS];        // output staging for coalesced store

    const int b = blockIdx.x;
    const int t = threadIdx.x;
    const int lane = t & 63;
    const int wv = t >> 6;

    // derived scalar params (wave-uniform)
    const float tin_prod  = p_tin_prod[0];
    const float tmil_prod = log1pf(expf(p_tmil_raw[0]));
    const float Aamp1     = 1.0f / log1pf(expf(p_aamp_raw[0])) + 1.0f;
    const float Aloop1    = 1.0f / log1pf(expf(p_aloop_raw[0])) + 1.0f;
    const float tau_out   = log1pf(expf(p_tout_raw[0]));
    const float wsf       = 1.0f / log1pf(expf(p_tsf_raw[0]));
    const float wdf       = 1.0f / log1pf(expf(p_tdiff_raw[0]));
    const float sprod = tin_prod + tmil_prod;          // (tin+tml)*I
    const float aprod = fmaf(Aamp1, tmil_prod, tin_prod); // (tin+Aamp1*tml)*I

    const float* rowI = it_eff + (size_t)b * SS;
    const float* rowT = ts     + (size_t)b * SS;

    // thread t owns steps k = 2t, 2t+1 (registers only — no LDS staging)
    const int k0 = 2 * t;
    const float2 I01 = *(const float2*)(rowI + k0);
    const float2 T01 = *(const float2*)(rowT + k0);
    const bool has2 = (k0 + 2 < SS);
    const float I2 = has2 ? rowI[k0 + 2] : 1.0f;
    const float T2 = has2 ? rowT[k0 + 2] : (T01.y + 1e-4f);
    const float uk0 = flog(I01.x);
    const float uk1 = flog(I01.y);
    const float uk2 = flog(I2);
    const float u0  = flog(rowI[0]);   // broadcast load

    Aff m1 = make_step(I01.y, T01.y - T01.x, uk0, uk1,
                       sprod, aprod, tau_out, Aloop1, wsf, wdf);
    Aff m2;
    if (has2) {
        m2 = make_step(I2, T2 - T01.y, uk1, uk2,
                       sprod, aprod, tau_out, Aloop1, wsf, wdf);
    } else {
        m2 = aff_identity();
    }

    Aff cur = aff_compose(m2, m1);

    // intra-wave Kogge-Stone inclusive scan over 64 lanes
#pragma unroll
    for (int d = 1; d < 64; d <<= 1) {
        Aff p = aff_shfl_up(cur, d);
        p = aff_sel_ident(p, lane >= d);
        cur = aff_compose(cur, p);
    }

    if (lane == 63) {
        float* dst = &swc[wv * 15];
        dst[0]=cur.a00; dst[1]=cur.a01; dst[2]=cur.a10; dst[3]=cur.a11;
        dst[4]=cur.a20; dst[5]=cur.a21; dst[6]=cur.a22;
        dst[7]=cur.a30; dst[8]=cur.a31; dst[9]=cur.a32; dst[10]=cur.a33;
        dst[11]=cur.c0; dst[12]=cur.c1; dst[13]=cur.c2; dst[14]=cur.c3;
    }
    __syncthreads();

    // wave-start state: apply preceding wave composites in order
    float x0 = 0.0f, x1 = u0, x2 = u0, x3 = u0;
    for (int j = 0; j < wv; ++j) {
        const float* m = &swc[j * 15];
        Aff wm;
        wm.a00=m[0]; wm.a01=m[1]; wm.a10=m[2]; wm.a11=m[3];
        wm.a20=m[4]; wm.a21=m[5]; wm.a22=m[6];
        wm.a30=m[7]; wm.a31=m[8]; wm.a32=m[9]; wm.a33=m[10];
        wm.c0=m[11]; wm.c1=m[12]; wm.c2=m[13]; wm.c3=m[14];
        aff_apply(wm, x0, x1, x2, x3);
    }

    // exclusive intra-wave prefix -> thread-start state
    Aff ex = aff_shfl_up(cur, 1);
    ex = aff_sel_ident(ex, lane >= 1);
    aff_apply(ex, x0, x1, x2, x3);

    // replay the 2 local steps
    aff_apply(m1, x0, x1, x2, x3);
    sy[k0 + 1] = x3;
    if (has2) {
        aff_apply(m2, x0, x1, x2, x3);
        sy[k0 + 2] = x3;
    }
    if (t == 0) sy[0] = u0;

    __syncthreads();

    const int base = b * SS;
    out[base + t]       = sy[t];
    out[base + 256 + t] = sy[256 + t];
}

extern "C" void kernel_launch(void* const* d_in, const int* in_sizes, int n_in,
                              void* d_out, int out_size, void* d_ws, size_t ws_size,
                              hipStream_t stream) {
    const float* it_eff = (const float*)d_in[0];
    const float* ts     = (const float*)d_in[1];
    const float* p2 = (const float*)d_in[2];
    const float* p3 = (const float*)d_in[3];
    const float* p4 = (const float*)d_in[4];
    const float* p5 = (const float*)d_in[5];
    const float* p6 = (const float*)d_in[6];
    const float* p7 = (const float*)d_in[7];
    const float* p8 = (const float*)d_in[8];
    float* out = (float*)d_out;

    pbw_kernel<<<dim3(BB), dim3(256), 0, stream>>>(
        it_eff, ts, p2, p3, p4, p5, p6, p7, p8, out);
}

// Round 4
// 97.674 us; speedup vs baseline: 3.9643x; 1.0555x over previous
//
#include <hip/hip_runtime.h>
#include <math.h>

namespace {
constexpr int BB = 2048;
constexpr int SS = 512;
constexpr int NSQ = 4;         // balanced norm <= 10.5; /16 -> theta <= 0.66
constexpr float SCV = 0.0625f; // 2^-NSQ
}

// fast 1-ulp hardware ops (tolerance is 6e-2; these are ~1e-7 rel)
__device__ __forceinline__ float frcp(float x) { return __builtin_amdgcn_rcpf(x); }
__device__ __forceinline__ float frsq(float x) { return __builtin_amdgcn_rsqf(x); }
__device__ __forceinline__ float flog(float x) {
    return __builtin_amdgcn_logf(x) * 0.69314718056f;
}

// affine map x -> A x + c, A block-lower-triangular with 11 nonzeros
struct Aff {
    float a00, a01, a10, a11;   // 2x2 oscillator block
    float a20, a21, a22;        // row 2
    float a30, a31, a32, a33;   // row 3
    float c0, c1, c2, c3;       // input vector
};

__device__ __forceinline__ Aff aff_identity() {
    Aff r;
    r.a00 = 1.f; r.a01 = 0.f; r.a10 = 0.f; r.a11 = 1.f;
    r.a20 = 0.f; r.a21 = 0.f; r.a22 = 1.f;
    r.a30 = 0.f; r.a31 = 0.f; r.a32 = 0.f; r.a33 = 1.f;
    r.c0 = 0.f; r.c1 = 0.f; r.c2 = 0.f; r.c3 = 0.f;
    return r;
}

// r = s o f  (apply f first, then s); structure closed, ~42 FMA
__device__ __forceinline__ Aff aff_compose(const Aff& s, const Aff& f) {
    Aff r;
    r.a00 = s.a00*f.a00 + s.a01*f.a10;
    r.a01 = s.a00*f.a01 + s.a01*f.a11;
    r.a10 = s.a10*f.a00 + s.a11*f.a10;
    r.a11 = s.a10*f.a01 + s.a11*f.a11;
    r.a20 = s.a20*f.a00 + s.a21*f.a10 + s.a22*f.a20;
    r.a21 = s.a20*f.a01 + s.a21*f.a11 + s.a22*f.a21;
    r.a22 = s.a22*f.a22;
    r.a30 = s.a30*f.a00 + s.a31*f.a10 + s.a32*f.a20 + s.a33*f.a30;
    r.a31 = s.a30*f.a01 + s.a31*f.a11 + s.a32*f.a21 + s.a33*f.a31;
    r.a32 = s.a32*f.a22 + s.a33*f.a32;
    r.a33 = s.a33*f.a33;
    r.c0 = s.a00*f.c0 + s.a01*f.c1 + s.c0;
    r.c1 = s.a10*f.c0 + s.a11*f.c1 + s.c1;
    r.c2 = s.a20*f.c0 + s.a21*f.c1 + s.a22*f.c2 + s.c2;
    r.c3 = s.a30*f.c0 + s.a31*f.c1 + s.a32*f.c2 + s.a33*f.c3 + s.c3;
    return r;
}

__device__ __forceinline__ Aff aff_shfl_up(const Aff& a, int d) {
    Aff r;
    r.a00 = __shfl_up(a.a00, d, 64); r.a01 = __shfl_up(a.a01, d, 64);
    r.a10 = __shfl_up(a.a10, d, 64); r.a11 = __shfl_up(a.a11, d, 64);
    r.a20 = __shfl_up(a.a20, d, 64); r.a21 = __shfl_up(a.a21, d, 64);
    r.a22 = __shfl_up(a.a22, d, 64);
    r.a30 = __shfl_up(a.a30, d, 64); r.a31 = __shfl_up(a.a31, d, 64);
    r.a32 = __shfl_up(a.a32, d, 64); r.a33 = __shfl_up(a.a33, d, 64);
    r.c0 = __shfl_up(a.c0, d, 64); r.c1 = __shfl_up(a.c1, d, 64);
    r.c2 = __shfl_up(a.c2, d, 64); r.c3 = __shfl_up(a.c3, d, 64);
    return r;
}

// branchless: keep p if ok, else identity
__device__ __forceinline__ Aff aff_sel_ident(const Aff& p, bool ok) {
    Aff r;
    r.a00 = ok ? p.a00 : 1.f; r.a01 = ok ? p.a01 : 0.f;
    r.a10 = ok ? p.a10 : 0.f; r.a11 = ok ? p.a11 : 1.f;
    r.a20 = ok ? p.a20 : 0.f; r.a21 = ok ? p.a21 : 0.f;
    r.a22 = ok ? p.a22 : 1.f;
    r.a30 = ok ? p.a30 : 0.f; r.a31 = ok ? p.a31 : 0.f;
    r.a32 = ok ? p.a32 : 0.f; r.a33 = ok ? p.a33 : 1.f;
    r.c0 = ok ? p.c0 : 0.f; r.c1 = ok ? p.c1 : 0.f;
    r.c2 = ok ? p.c2 : 0.f; r.c3 = ok ? p.c3 : 0.f;
    return r;
}

// x <- A x + c
__device__ __forceinline__ void aff_apply(const Aff& m, float& x0, float& x1,
                                          float& x2, float& x3) {
    const float y0 = m.a00*x0 + m.a01*x1 + m.c0;
    const float y1 = m.a10*x0 + m.a11*x1 + m.c1;
    const float y2 = m.a20*x0 + m.a21*x1 + m.a22*x2 + m.c2;
    const float y3 = m.a30*x0 + m.a31*x1 + m.a32*x2 + m.a33*x3 + m.c3;
    x0 = y0; x1 = y1; x2 = y2; x3 = y3;
}

// one discretization step:
//   E = expm(M), M = balanced A*dt, via degree-6 Taylor on M/16 + 4 squarings
//   G1 = phi1(M) g = M^{-1}(E - I) g        (exact identity, no series)
//   G2 = phi2(M) g = M^{-1}(G1 - g)
// Balanced M (D = diag(w,1,1,1)) is invertible: osc det = w^2 dt^2, w dt>=0.3;
// low-pass block triangular with diag -wsf dt, -wdf dt.
__device__ __forceinline__ Aff make_step(
    float Iss, float dt, float uk, float uk1,
    float sprod, float aprod, float tau_out, float Aloop1,
    float wsf, float wdf, float rwsf, float rwdf)
{
    const float rI  = frcp(Iss);
    const float s   = sprod * rI;                 // tin + tml
    const float idn = frcp(s * tau_out);
    const float a   = fmaf(aprod, rI, tau_out) * idn;
    const float w2  = Aloop1 * idn;
    const float iw  = frsq(w2);
    const float w   = w2 * iw;

    const float dts = dt * SCV;
    const float f00 = -a * dts;
    const float f01 = -w * dts;
    const float f10 =  w * dts;
    const float f21 =  wsf * dts;
    const float f22 = -f21;
    const float f32 =  wdf * dts;
    const float f33 = -f32;

    // E = exp(Fs), degree-6 Taylor (Horner); theta<=0.66 -> trunc ~1e-5
    float t00 = fmaf(f00, 1.0f/6.0f, 1.0f), t01 = f01 * (1.0f/6.0f);
    float t10 = f10 * (1.0f/6.0f),          t11 = 1.0f;
    float c00 = 0.0f, c01 = f21 * (1.0f/6.0f), c10 = 0.0f, c11 = 0.0f;
    float l00 = fmaf(f22, 1.0f/6.0f, 1.0f);
    float l10 = f32 * (1.0f/6.0f);
    float l11 = fmaf(f33, 1.0f/6.0f, 1.0f);
#pragma unroll
    for (int m = 5; m >= 1; --m) {
        const float rm = 1.0f / (float)m;  // folds to literal under unroll
        const float p00 = f00*t00 + f01*t10;
        const float p01 = f00*t01 + f01*t11;
        const float p10 = f10*t00;
        const float p11 = f10*t01;
        const float q00 = f21*t10 + f22*c00;
        const float q01 = f21*t11 + f22*c01;
        const float q10 = f32*c00 + f33*c10;
        const float q11 = f32*c01 + f33*c11;
        const float m00 = f22*l00;
        const float m10 = f32*l00 + f33*l10;
        const float m11 = f33*l11;
        t00 = fmaf(p00, rm, 1.0f); t01 = p01*rm;
        t10 = p10*rm;              t11 = fmaf(p11, rm, 1.0f);
        c00 = q00*rm; c01 = q01*rm; c10 = q10*rm; c11 = q11*rm;
        l00 = fmaf(m00, rm, 1.0f); l10 = m10*rm; l11 = fmaf(m11, rm, 1.0f);
    }

    // 4 squarings — matrix only (G's come from solves afterwards)
#pragma unroll
    for (int i = 0; i < NSQ; ++i) {
        const float p00 = t00*t00 + t01*t10;
        const float p01 = t00*t01 + t01*t11;
        const float p10 = t10*t00 + t11*t10;
        const float p11 = t10*t01 + t11*t11;
        const float q00 = c00*t00 + c01*t10 + l00*c00;
        const float q01 = c00*t01 + c01*t11 + l00*c01;
        const float q10 = c10*t00 + c11*t10 + l10*c00 + l11*c10;
        const float q11 = c10*t01 + c11*t11 + l10*c01 + l11*c11;
        const float m00 = l00*l00;
        const float m10 = l10*l00 + l11*l10;
        const float m11 = l11*l11;
        t00 = p00; t01 = p01; t10 = p10; t11 = p11;
        c00 = q00; c01 = q01; c10 = q10; c11 = q11;
        l00 = m00; l10 = m10; l11 = m11;
    }

    // --- phi1/phi2 via exact back-substitution solves (balanced space) ---
    // g = (w*dt, 0,0,0); scale-free: y0 = t10, y1 = -((t00-1) + (a/w) t10), ...
    const float aw  = a * iw;           // a/w  (<= ~6.1 on this data)
    const float rdt = frcp(dt);
    const float rF  = iw * rdt;         // 1/(w dt)
    const float rS  = rwsf * rdt;       // 1/(wsf dt)
    const float rD  = rwdf * rdt;       // 1/(wdf dt)
    const float wS  = w * rwsf;         // w/wsf
    const float wD  = w * rwdf;         // w/wdf
    const float g0u = w * dt;

    // G1 = M^{-1}(E-I)g  (balanced)
    const float y0 = t10;
    const float y1 = -fmaf(aw, t10, t00 - 1.0f);
    const float y2 = fmaf(-wS, c00, y1);
    const float y3 = fmaf(-wD, c10, y2);
    // G2 = M^{-1}(G1 - g)  (balanced)
    const float s0 = y0 - g0u;
    const float z0 = y1 * rF;
    const float z1 = -fmaf(aw, z0, rF * s0);
    const float z2 = fmaf(-y2, rS, z1);
    const float z3 = fmaf(-y3, rD, z2);

    // unbalance: Ad = D E D^-1, D = diag(w,1,1,1); G *= D
    Aff r;
    r.a00 = t00;      r.a01 = w * t01;
    r.a10 = t10 * iw; r.a11 = t11;
    r.a20 = c00 * iw; r.a21 = c01; r.a22 = l00;
    r.a30 = c10 * iw; r.a31 = c11; r.a32 = l10; r.a33 = l11;
    const float G10 = w * y0, G20 = w * z0;
    // c = G1*uk + G2*(uk1-uk)   (== Bd*uk + Bt*uk1)
    const float du = uk1 - uk;
    r.c0 = fmaf(G10, uk, G20 * du);
    r.c1 = fmaf(y1,  uk, z1 * du);
    r.c2 = fmaf(y2,  uk, z2 * du);
    r.c3 = fmaf(y3,  uk, z3 * du);
    return r;
}

__global__ __launch_bounds__(256) void pbw_kernel(
    const float* __restrict__ it_eff,
    const float* __restrict__ ts,
    const float* __restrict__ p_tin_prod,
    const float* __restrict__ p_tmil_raw,
    const float* __restrict__ p_aamp_raw,
    const float* __restrict__ p_aloop_raw,
    const float* __restrict__ p_tout_raw,
    const float* __restrict__ p_tsf_raw,
    const float* __restrict__ p_tdiff_raw,
    float* __restrict__ out)
{
    __shared__ float swc[4 * 15];   // per-wave composites
    __shared__ float sy[SS];        // output staging for coalesced store

    const int b = blockIdx.x;
    const int t = threadIdx.x;
    const int lane = t & 63;
    const int wv = t >> 6;

    // derived scalar params (wave-uniform)
    const float tin_prod  = p_tin_prod[0];
    const float tmil_prod = log1pf(expf(p_tmil_raw[0]));
    const float Aamp1     = 1.0f / log1pf(expf(p_aamp_raw[0])) + 1.0f;
    const float Aloop1    = 1.0f / log1pf(expf(p_aloop_raw[0])) + 1.0f;
    const float tau_out   = log1pf(expf(p_tout_raw[0]));
    const float sp_sf     = log1pf(expf(p_tsf_raw[0]));
    const float sp_df     = log1pf(expf(p_tdiff_raw[0]));
    const float wsf       = 1.0f / sp_sf;
    const float wdf       = 1.0f / sp_df;
    const float sprod = tin_prod + tmil_prod;             // (tin+tml)*I
    const float aprod = fmaf(Aamp1, tmil_prod, tin_prod); // (tin+Aamp1*tml)*I

    const float* rowI = it_eff + (size_t)b * SS;
    const float* rowT = ts     + (size_t)b * SS;

    // thread t owns steps k = 2t, 2t+1 (registers only — no LDS staging)
    const int k0 = 2 * t;
    const float2 I01 = *(const float2*)(rowI + k0);
    const float2 T01 = *(const float2*)(rowT + k0);
    const bool has2 = (k0 + 2 < SS);
    const float I2 = has2 ? rowI[k0 + 2] : 1.0f;
    const float T2 = has2 ? rowT[k0 + 2] : (T01.y + 1e-4f);
    const float uk0 = flog(I01.x);
    const float uk1 = flog(I01.y);
    const float uk2 = flog(I2);
    const float u0  = flog(rowI[0]);   // broadcast load

    Aff m1 = make_step(I01.y, T01.y - T01.x, uk0, uk1,
                       sprod, aprod, tau_out, Aloop1, wsf, wdf, sp_sf, sp_df);
    Aff m2;
    if (has2) {
        m2 = make_step(I2, T2 - T01.y, uk1, uk2,
                       sprod, aprod, tau_out, Aloop1, wsf, wdf, sp_sf, sp_df);
    } else {
        m2 = aff_identity();
    }

    Aff cur = aff_compose(m2, m1);

    // intra-wave Kogge-Stone inclusive scan over 64 lanes
#pragma unroll
    for (int d = 1; d < 64; d <<= 1) {
        Aff p = aff_shfl_up(cur, d);
        p = aff_sel_ident(p, lane >= d);
        cur = aff_compose(cur, p);
    }

    if (lane == 63) {
        float* dst = &swc[wv * 15];
        dst[0]=cur.a00; dst[1]=cur.a01; dst[2]=cur.a10; dst[3]=cur.a11;
        dst[4]=cur.a20; dst[5]=cur.a21; dst[6]=cur.a22;
        dst[7]=cur.a30; dst[8]=cur.a31; dst[9]=cur.a32; dst[10]=cur.a33;
        dst[11]=cur.c0; dst[12]=cur.c1; dst[13]=cur.c2; dst[14]=cur.c3;
    }
    __syncthreads();

    // wave-start state: apply preceding wave composites in order
    float x0 = 0.0f, x1 = u0, x2 = u0, x3 = u0;
    for (int j = 0; j < wv; ++j) {
        const float* m = &swc[j * 15];
        Aff wm;
        wm.a00=m[0]; wm.a01=m[1]; wm.a10=m[2]; wm.a11=m[3];
        wm.a20=m[4]; wm.a21=m[5]; wm.a22=m[6];
        wm.a30=m[7]; wm.a31=m[8]; wm.a32=m[9]; wm.a33=m[10];
        wm.c0=m[11]; wm.c1=m[12]; wm.c2=m[13]; wm.c3=m[14];
        aff_apply(wm, x0, x1, x2, x3);
    }

    // exclusive intra-wave prefix -> thread-start state
    Aff ex = aff_shfl_up(cur, 1);
    ex = aff_sel_ident(ex, lane >= 1);
    aff_apply(ex, x0, x1, x2, x3);

    // replay the 2 local steps
    aff_apply(m1, x0, x1, x2, x3);
    sy[k0 + 1] = x3;
    if (has2) {
        aff_apply(m2, x0, x1, x2, x3);
        sy[k0 + 2] = x3;
    }
    if (t == 0) sy[0] = u0;

    __syncthreads();

    const int base = b * SS;
    out[base + t]       = sy[t];
    out[base + 256 + t] = sy[256 + t];
}

extern "C" void kernel_launch(void* const* d_in, const int* in_sizes, int n_in,
                              void* d_out, int out_size, void* d_ws, size_t ws_size,
                              hipStream_t stream) {
    const float* it_eff = (const float*)d_in[0];
    const float* ts     = (const float*)d_in[1];
    const float* p2 = (const float*)d_in[2];
    const float* p3 = (const float*)d_in[3];
    const float* p4 = (const float*)d_in[4];
    const float* p5 = (const float*)d_in[5];
    const float* p6 = (const float*)d_in[6];
    const float* p7 = (const float*)d_in[7];
    const float* p8 = (const float*)d_in[8];
    float* out = (float*)d_out;

    pbw_kernel<<<dim3(BB), dim3(256), 0, stream>>>(
        it_eff, ts, p2, p3, p4, p5, p6, p7, p8, out);
}

// Round 5
// 91.597 us; speedup vs baseline: 4.2273x; 1.0663x over previous
//
#include <hip/hip_runtime.h>
#include <math.h>

namespace {
constexpr int BB  = 2048;
constexpr int SS  = 512;
constexpr int TPB = 128;       // 4 steps per thread
constexpr int NSQ = 4;         // balanced norm <= 10.5; /16 -> theta <= 0.66
constexpr float SCV = 0.0625f; // 2^-NSQ
}

// fast 1-ulp hardware ops (tolerance is 6e-2; these are ~1e-7 rel)
__device__ __forceinline__ float frcp(float x) { return __builtin_amdgcn_rcpf(x); }
__device__ __forceinline__ float frsq(float x) { return __builtin_amdgcn_rsqf(x); }
__device__ __forceinline__ float flog(float x) {
    return __builtin_amdgcn_logf(x) * 0.69314718056f;
}

// affine map x -> A x + c, A block-lower-triangular with 11 nonzeros
struct Aff {
    float a00, a01, a10, a11;   // 2x2 oscillator block
    float a20, a21, a22;        // row 2
    float a30, a31, a32, a33;   // row 3
    float c0, c1, c2, c3;       // input vector
};

__device__ __forceinline__ Aff aff_identity() {
    Aff r;
    r.a00 = 1.f; r.a01 = 0.f; r.a10 = 0.f; r.a11 = 1.f;
    r.a20 = 0.f; r.a21 = 0.f; r.a22 = 1.f;
    r.a30 = 0.f; r.a31 = 0.f; r.a32 = 0.f; r.a33 = 1.f;
    r.c0 = 0.f; r.c1 = 0.f; r.c2 = 0.f; r.c3 = 0.f;
    return r;
}

// r = s o f  (apply f first, then s); structure closed, ~42 FMA
__device__ __forceinline__ Aff aff_compose(const Aff& s, const Aff& f) {
    Aff r;
    r.a00 = s.a00*f.a00 + s.a01*f.a10;
    r.a01 = s.a00*f.a01 + s.a01*f.a11;
    r.a10 = s.a10*f.a00 + s.a11*f.a10;
    r.a11 = s.a10*f.a01 + s.a11*f.a11;
    r.a20 = s.a20*f.a00 + s.a21*f.a10 + s.a22*f.a20;
    r.a21 = s.a20*f.a01 + s.a21*f.a11 + s.a22*f.a21;
    r.a22 = s.a22*f.a22;
    r.a30 = s.a30*f.a00 + s.a31*f.a10 + s.a32*f.a20 + s.a33*f.a30;
    r.a31 = s.a30*f.a01 + s.a31*f.a11 + s.a32*f.a21 + s.a33*f.a31;
    r.a32 = s.a32*f.a22 + s.a33*f.a32;
    r.a33 = s.a33*f.a33;
    r.c0 = s.a00*f.c0 + s.a01*f.c1 + s.c0;
    r.c1 = s.a10*f.c0 + s.a11*f.c1 + s.c1;
    r.c2 = s.a20*f.c0 + s.a21*f.c1 + s.a22*f.c2 + s.c2;
    r.c3 = s.a30*f.c0 + s.a31*f.c1 + s.a32*f.c2 + s.a33*f.c3 + s.c3;
    return r;
}

__device__ __forceinline__ Aff aff_shfl_up(const Aff& a, int d) {
    Aff r;
    r.a00 = __shfl_up(a.a00, d, 64); r.a01 = __shfl_up(a.a01, d, 64);
    r.a10 = __shfl_up(a.a10, d, 64); r.a11 = __shfl_up(a.a11, d, 64);
    r.a20 = __shfl_up(a.a20, d, 64); r.a21 = __shfl_up(a.a21, d, 64);
    r.a22 = __shfl_up(a.a22, d, 64);
    r.a30 = __shfl_up(a.a30, d, 64); r.a31 = __shfl_up(a.a31, d, 64);
    r.a32 = __shfl_up(a.a32, d, 64); r.a33 = __shfl_up(a.a33, d, 64);
    r.c0 = __shfl_up(a.c0, d, 64); r.c1 = __shfl_up(a.c1, d, 64);
    r.c2 = __shfl_up(a.c2, d, 64); r.c3 = __shfl_up(a.c3, d, 64);
    return r;
}

// branchless: keep p if ok, else identity
__device__ __forceinline__ Aff aff_sel_ident(const Aff& p, bool ok) {
    Aff r;
    r.a00 = ok ? p.a00 : 1.f; r.a01 = ok ? p.a01 : 0.f;
    r.a10 = ok ? p.a10 : 0.f; r.a11 = ok ? p.a11 : 1.f;
    r.a20 = ok ? p.a20 : 0.f; r.a21 = ok ? p.a21 : 0.f;
    r.a22 = ok ? p.a22 : 1.f;
    r.a30 = ok ? p.a30 : 0.f; r.a31 = ok ? p.a31 : 0.f;
    r.a32 = ok ? p.a32 : 0.f; r.a33 = ok ? p.a33 : 1.f;
    r.c0 = ok ? p.c0 : 0.f; r.c1 = ok ? p.c1 : 0.f;
    r.c2 = ok ? p.c2 : 0.f; r.c3 = ok ? p.c3 : 0.f;
    return r;
}

// x <- A x + c
__device__ __forceinline__ void aff_apply(const Aff& m, float& x0, float& x1,
                                          float& x2, float& x3) {
    const float y0 = m.a00*x0 + m.a01*x1 + m.c0;
    const float y1 = m.a10*x0 + m.a11*x1 + m.c1;
    const float y2 = m.a20*x0 + m.a21*x1 + m.a22*x2 + m.c2;
    const float y3 = m.a30*x0 + m.a31*x1 + m.a32*x2 + m.a33*x3 + m.c3;
    x0 = y0; x1 = y1; x2 = y2; x3 = y3;
}

// one discretization step:
//   E = expm(M), M = balanced A*dt, via degree-6 Taylor on M/16 + 4 squarings
//   G1 = phi1(M) g = M^{-1}(E - I) g        (exact identity, no series)
//   G2 = phi2(M) g = M^{-1}(G1 - g)
__device__ __forceinline__ Aff make_step(
    float Iss, float dt, float uk, float uk1,
    float sprod, float aprod, float tau_out, float Aloop1,
    float wsf, float wdf, float rwsf, float rwdf)
{
    const float rI  = frcp(Iss);
    const float s   = sprod * rI;                 // tin + tml
    const float idn = frcp(s * tau_out);
    const float a   = fmaf(aprod, rI, tau_out) * idn;
    const float w2  = Aloop1 * idn;
    const float iw  = frsq(w2);
    const float w   = w2 * iw;

    const float dts = dt * SCV;
    const float f00 = -a * dts;
    const float f01 = -w * dts;
    const float f10 =  w * dts;
    const float f21 =  wsf * dts;
    const float f22 = -f21;
    const float f32 =  wdf * dts;
    const float f33 = -f32;

    // E = exp(Fs), degree-6 Taylor (Horner); theta<=0.66 -> trunc ~1e-5
    float t00 = fmaf(f00, 1.0f/6.0f, 1.0f), t01 = f01 * (1.0f/6.0f);
    float t10 = f10 * (1.0f/6.0f),          t11 = 1.0f;
    float c00 = 0.0f, c01 = f21 * (1.0f/6.0f), c10 = 0.0f, c11 = 0.0f;
    float l00 = fmaf(f22, 1.0f/6.0f, 1.0f);
    float l10 = f32 * (1.0f/6.0f);
    float l11 = fmaf(f33, 1.0f/6.0f, 1.0f);
#pragma unroll
    for (int m = 5; m >= 1; --m) {
        const float rm = 1.0f / (float)m;  // folds to literal under unroll
        const float p00 = f00*t00 + f01*t10;
        const float p01 = f00*t01 + f01*t11;
        const float p10 = f10*t00;
        const float p11 = f10*t01;
        const float q00 = f21*t10 + f22*c00;
        const float q01 = f21*t11 + f22*c01;
        const float q10 = f32*c00 + f33*c10;
        const float q11 = f32*c01 + f33*c11;
        const float m00 = f22*l00;
        const float m10 = f32*l00 + f33*l10;
        const float m11 = f33*l11;
        t00 = fmaf(p00, rm, 1.0f); t01 = p01*rm;
        t10 = p10*rm;              t11 = fmaf(p11, rm, 1.0f);
        c00 = q00*rm; c01 = q01*rm; c10 = q10*rm; c11 = q11*rm;
        l00 = fmaf(m00, rm, 1.0f); l10 = m10*rm; l11 = fmaf(m11, rm, 1.0f);
    }

    // 4 squarings — matrix only
#pragma unroll
    for (int i = 0; i < NSQ; ++i) {
        const float p00 = t00*t00 + t01*t10;
        const float p01 = t00*t01 + t01*t11;
        const float p10 = t10*t00 + t11*t10;
        const float p11 = t10*t01 + t11*t11;
        const float q00 = c00*t00 + c01*t10 + l00*c00;
        const float q01 = c00*t01 + c01*t11 + l00*c01;
        const float q10 = c10*t00 + c11*t10 + l10*c00 + l11*c10;
        const float q11 = c10*t01 + c11*t11 + l10*c01 + l11*c11;
        const float m00 = l00*l00;
        const float m10 = l10*l00 + l11*l10;
        const float m11 = l11*l11;
        t00 = p00; t01 = p01; t10 = p10; t11 = p11;
        c00 = q00; c01 = q01; c10 = q10; c11 = q11;
        l00 = m00; l10 = m10; l11 = m11;
    }

    // phi1/phi2 via exact back-substitution solves (balanced space)
    const float aw  = a * iw;           // a/w
    const float rdt = frcp(dt);
    const float rF  = iw * rdt;         // 1/(w dt)
    const float rS  = rwsf * rdt;       // 1/(wsf dt)
    const float rD  = rwdf * rdt;       // 1/(wdf dt)
    const float wS  = w * rwsf;         // w/wsf
    const float wD  = w * rwdf;         // w/wdf
    const float g0u = w * dt;

    // G1 = M^{-1}(E-I)g  (balanced)
    const float y0 = t10;
    const float y1 = -fmaf(aw, t10, t00 - 1.0f);
    const float y2 = fmaf(-wS, c00, y1);
    const float y3 = fmaf(-wD, c10, y2);
    // G2 = M^{-1}(G1 - g)  (balanced)
    const float s0 = y0 - g0u;
    const float z0 = y1 * rF;
    const float z1 = -fmaf(aw, z0, rF * s0);
    const float z2 = fmaf(-y2, rS, z1);
    const float z3 = fmaf(-y3, rD, z2);

    // unbalance: Ad = D E D^-1, D = diag(w,1,1,1); G *= D
    Aff r;
    r.a00 = t00;      r.a01 = w * t01;
    r.a10 = t10 * iw; r.a11 = t11;
    r.a20 = c00 * iw; r.a21 = c01; r.a22 = l00;
    r.a30 = c10 * iw; r.a31 = c11; r.a32 = l10; r.a33 = l11;
    const float G10 = w * y0, G20 = w * z0;
    // c = G1*uk + G2*(uk1-uk)   (== Bd*uk + Bt*uk1)
    const float du = uk1 - uk;
    r.c0 = fmaf(G10, uk, G20 * du);
    r.c1 = fmaf(y1,  uk, z1 * du);
    r.c2 = fmaf(y2,  uk, z2 * du);
    r.c3 = fmaf(y3,  uk, z3 * du);
    return r;
}

__global__ __launch_bounds__(TPB) void pbw_kernel(
    const float* __restrict__ it_eff,
    const float* __restrict__ ts,
    const float* __restrict__ p_tin_prod,
    const float* __restrict__ p_tmil_raw,
    const float* __restrict__ p_aamp_raw,
    const float* __restrict__ p_aloop_raw,
    const float* __restrict__ p_tout_raw,
    const float* __restrict__ p_tsf_raw,
    const float* __restrict__ p_tdiff_raw,
    float* __restrict__ out)
{
    __shared__ float swc[15];       // wave-0 composite (2 waves per block)
    __shared__ float sy[SS + 4];    // output staging (+4 pad for tail thread)

    const int b = blockIdx.x;
    const int t = threadIdx.x;
    const int lane = t & 63;
    const int wv = t >> 6;

    // derived scalar params (wave-uniform)
    const float tin_prod  = p_tin_prod[0];
    const float tmil_prod = log1pf(expf(p_tmil_raw[0]));
    const float Aamp1     = 1.0f / log1pf(expf(p_aamp_raw[0])) + 1.0f;
    const float Aloop1    = 1.0f / log1pf(expf(p_aloop_raw[0])) + 1.0f;
    const float tau_out   = log1pf(expf(p_tout_raw[0]));
    const float sp_sf     = log1pf(expf(p_tsf_raw[0]));
    const float sp_df     = log1pf(expf(p_tdiff_raw[0]));
    const float wsf       = 1.0f / sp_sf;
    const float wdf       = 1.0f / sp_df;
    const float sprod = tin_prod + tmil_prod;             // (tin+tml)*I
    const float aprod = fmaf(Aamp1, tmil_prod, tin_prod); // (tin+Aamp1*tml)*I

    const float* rowI = it_eff + (size_t)b * SS;
    const float* rowT = ts     + (size_t)b * SS;

    // thread t owns steps k = 4t .. 4t+3 (last thread: 3 real + identity)
    const int k0 = 4 * t;
    const float4 I4 = *(const float4*)(rowI + k0);
    const float4 T4 = *(const float4*)(rowT + k0);
    const bool last = (t == TPB - 1);
    const float I_4 = last ? 1.0f : rowI[k0 + 4];
    const float T_4 = last ? (T4.w + 1e-4f) : rowT[k0 + 4];

    const float u_0 = flog(I4.x);
    const float u_1 = flog(I4.y);
    const float u_2 = flog(I4.z);
    const float u_3 = flog(I4.w);
    const float u_4 = flog(I_4);
    const float u0  = flog(rowI[0]);   // broadcast load

    Aff m0 = make_step(I4.y, T4.y - T4.x, u_0, u_1,
                       sprod, aprod, tau_out, Aloop1, wsf, wdf, sp_sf, sp_df);
    Aff m1 = make_step(I4.z, T4.z - T4.y, u_1, u_2,
                       sprod, aprod, tau_out, Aloop1, wsf, wdf, sp_sf, sp_df);
    Aff m2 = make_step(I4.w, T4.w - T4.z, u_2, u_3,
                       sprod, aprod, tau_out, Aloop1, wsf, wdf, sp_sf, sp_df);
    Aff m3 = make_step(I_4, T_4 - T4.w, u_3, u_4,
                       sprod, aprod, tau_out, Aloop1, wsf, wdf, sp_sf, sp_df);
    if (last) m3 = aff_identity();

    // local composite (tree for ILP)
    const Aff c01 = aff_compose(m1, m0);
    const Aff c23 = aff_compose(m3, m2);
    Aff cur = aff_compose(c23, c01);

    // intra-wave Kogge-Stone inclusive scan over 64 lanes
#pragma unroll
    for (int d = 1; d < 64; d <<= 1) {
        Aff p = aff_shfl_up(cur, d);
        p = aff_sel_ident(p, lane >= d);
        cur = aff_compose(cur, p);
    }

    if (wv == 0 && lane == 63) {
        swc[0]=cur.a00; swc[1]=cur.a01; swc[2]=cur.a10; swc[3]=cur.a11;
        swc[4]=cur.a20; swc[5]=cur.a21; swc[6]=cur.a22;
        swc[7]=cur.a30; swc[8]=cur.a31; swc[9]=cur.a32; swc[10]=cur.a33;
        swc[11]=cur.c0; swc[12]=cur.c1; swc[13]=cur.c2; swc[14]=cur.c3;
    }
    __syncthreads();

    // wave-start state
    float x0 = 0.0f, x1 = u0, x2 = u0, x3 = u0;
    if (wv == 1) {
        Aff wm;
        wm.a00=swc[0]; wm.a01=swc[1]; wm.a10=swc[2]; wm.a11=swc[3];
        wm.a20=swc[4]; wm.a21=swc[5]; wm.a22=swc[6];
        wm.a30=swc[7]; wm.a31=swc[8]; wm.a32=swc[9]; wm.a33=swc[10];
        wm.c0=swc[11]; wm.c1=swc[12]; wm.c2=swc[13]; wm.c3=swc[14];
        aff_apply(wm, x0, x1, x2, x3);
    }

    // exclusive intra-wave prefix -> thread-start state
    Aff ex = aff_shfl_up(cur, 1);
    ex = aff_sel_ident(ex, lane >= 1);
    aff_apply(ex, x0, x1, x2, x3);

    // replay the 4 local steps
    aff_apply(m0, x0, x1, x2, x3); sy[k0 + 1] = x3;
    aff_apply(m1, x0, x1, x2, x3); sy[k0 + 2] = x3;
    aff_apply(m2, x0, x1, x2, x3); sy[k0 + 3] = x3;
    aff_apply(m3, x0, x1, x2, x3); sy[k0 + 4] = x3;   // k0+4==512 lands in pad
    if (t == 0) sy[0] = u0;

    __syncthreads();

    // coalesced float4 store
    float4* po = (float4*)(out + (size_t)b * SS);
    po[t] = *(const float4*)&sy[4 * t];
}

extern "C" void kernel_launch(void* const* d_in, const int* in_sizes, int n_in,
                              void* d_out, int out_size, void* d_ws, size_t ws_size,
                              hipStream_t stream) {
    const float* it_eff = (const float*)d_in[0];
    const float* ts     = (const float*)d_in[1];
    const float* p2 = (const float*)d_in[2];
    const float* p3 = (const float*)d_in[3];
    const float* p4 = (const float*)d_in[4];
    const float* p5 = (const float*)d_in[5];
    const float* p6 = (const float*)d_in[6];
    const float* p7 = (const float*)d_in[7];
    const float* p8 = (const float*)d_in[8];
    float* out = (float*)d_out;

    pbw_kernel<<<dim3(BB), dim3(TPB), 0, stream>>>(
        it_eff, ts, p2, p3, p4, p5, p6, p7, p8, out);
}

// Round 6
// 90.680 us; speedup vs baseline: 4.2701x; 1.0101x over previous
//
#include <hip/hip_runtime.h>
#include <math.h>

namespace {
constexpr int BB  = 2048;
constexpr int SS  = 512;
constexpr int TPB = 128;       // 4 steps per thread
constexpr int NSQ = 4;         // balanced norm <= 10.5; /16 -> theta <= 0.66
constexpr float SCV = 0.0625f; // 2^-NSQ
}

// fast 1-ulp hardware ops (tolerance is 6e-2; these are ~1e-7 rel)
__device__ __forceinline__ float frcp(float x) { return __builtin_amdgcn_rcpf(x); }
__device__ __forceinline__ float frsq(float x) { return __builtin_amdgcn_rsqf(x); }
__device__ __forceinline__ float flog(float x) {
    return __builtin_amdgcn_logf(x) * 0.69314718056f;
}

// full per-step coefficients (output of make_step)
struct Aff {
    float a00, a01, a10, a11;   // 2x2 oscillator block T
    float a20, a21, a22;        // row 2
    float a30, a31, a32, a33;   // row 3
    float c0, c1, c2, c3;       // input vector
};

__device__ __forceinline__ Aff aff_identity() {
    Aff r;
    r.a00 = 1.f; r.a01 = 0.f; r.a10 = 0.f; r.a11 = 1.f;
    r.a20 = 0.f; r.a21 = 0.f; r.a22 = 1.f;
    r.a30 = 0.f; r.a31 = 0.f; r.a32 = 0.f; r.a33 = 1.f;
    r.c0 = 0.f; r.c1 = 0.f; r.c2 = 0.f; r.c3 = 0.f;
    return r;
}

// ---- oscillator (top 2x2) affine scan primitives ----
struct Osc { float a00, a01, a10, a11, c0, c1; };

__device__ __forceinline__ Osc osc_compose(const Osc& s, const Osc& f) {
    Osc r;
    r.a00 = s.a00*f.a00 + s.a01*f.a10;
    r.a01 = s.a00*f.a01 + s.a01*f.a11;
    r.a10 = s.a10*f.a00 + s.a11*f.a10;
    r.a11 = s.a10*f.a01 + s.a11*f.a11;
    r.c0  = s.a00*f.c0 + s.a01*f.c1 + s.c0;
    r.c1  = s.a10*f.c0 + s.a11*f.c1 + s.c1;
    return r;
}
__device__ __forceinline__ Osc osc_shfl_up(const Osc& a, int d) {
    Osc r;
    r.a00 = __shfl_up(a.a00, d, 64); r.a01 = __shfl_up(a.a01, d, 64);
    r.a10 = __shfl_up(a.a10, d, 64); r.a11 = __shfl_up(a.a11, d, 64);
    r.c0  = __shfl_up(a.c0,  d, 64); r.c1  = __shfl_up(a.c1,  d, 64);
    return r;
}
__device__ __forceinline__ Osc osc_sel(const Osc& p, bool ok) {
    Osc r;
    r.a00 = ok ? p.a00 : 1.f; r.a01 = ok ? p.a01 : 0.f;
    r.a10 = ok ? p.a10 : 0.f; r.a11 = ok ? p.a11 : 1.f;
    r.c0  = ok ? p.c0  : 0.f; r.c1  = ok ? p.c1  : 0.f;
    return r;
}
__device__ __forceinline__ void osc_apply(const Osc& m, float& v0, float& v1) {
    const float y0 = m.a00*v0 + m.a01*v1 + m.c0;
    const float y1 = m.a10*v0 + m.a11*v1 + m.c1;
    v0 = y0; v1 = y1;
}

// ---- lower-triangular (bottom 2x2) affine scan primitives ----
struct Low { float l00, l10, l11, c0, c1; };

__device__ __forceinline__ Low low_compose(const Low& s, const Low& f) {
    Low r;
    r.l00 = s.l00*f.l00;
    r.l10 = s.l10*f.l00 + s.l11*f.l10;
    r.l11 = s.l11*f.l11;
    r.c0  = fmaf(s.l00, f.c0, s.c0);
    r.c1  = fmaf(s.l10, f.c0, fmaf(s.l11, f.c1, s.c1));
    return r;
}
__device__ __forceinline__ Low low_shfl_up(const Low& a, int d) {
    Low r;
    r.l00 = __shfl_up(a.l00, d, 64); r.l10 = __shfl_up(a.l10, d, 64);
    r.l11 = __shfl_up(a.l11, d, 64);
    r.c0  = __shfl_up(a.c0,  d, 64); r.c1  = __shfl_up(a.c1,  d, 64);
    return r;
}
__device__ __forceinline__ Low low_sel(const Low& p, bool ok) {
    Low r;
    r.l00 = ok ? p.l00 : 1.f; r.l10 = ok ? p.l10 : 0.f;
    r.l11 = ok ? p.l11 : 1.f;
    r.c0  = ok ? p.c0  : 0.f; r.c1  = ok ? p.c1  : 0.f;
    return r;
}
__device__ __forceinline__ void low_apply(const Low& m, float& x2, float& x3) {
    const float y2 = fmaf(m.l00, x2, m.c0);
    const float y3 = m.l10*x2 + m.l11*x3 + m.c1;
    x2 = y2; x3 = y3;
}

// one discretization step:
//   E = expm(M), M = balanced A*dt, via degree-6 Taylor on M/16 + 4 squarings
//   G1 = phi1(M) g = M^{-1}(E - I) g        (exact identity, no series)
//   G2 = phi2(M) g = M^{-1}(G1 - g)
__device__ __forceinline__ Aff make_step(
    float Iss, float dt, float uk, float uk1,
    float sprod, float aprod, float tau_out, float Aloop1,
    float wsf, float wdf, float rwsf, float rwdf)
{
    const float rI  = frcp(Iss);
    const float s   = sprod * rI;                 // tin + tml
    const float idn = frcp(s * tau_out);
    const float a   = fmaf(aprod, rI, tau_out) * idn;
    const float w2  = Aloop1 * idn;
    const float iw  = frsq(w2);
    const float w   = w2 * iw;

    const float dts = dt * SCV;
    const float f00 = -a * dts;
    const float f01 = -w * dts;
    const float f10 =  w * dts;
    const float f21 =  wsf * dts;
    const float f22 = -f21;
    const float f32 =  wdf * dts;
    const float f33 = -f32;

    // E = exp(Fs), degree-6 Taylor (Horner); theta<=0.66 -> trunc ~1e-5
    float t00 = fmaf(f00, 1.0f/6.0f, 1.0f), t01 = f01 * (1.0f/6.0f);
    float t10 = f10 * (1.0f/6.0f),          t11 = 1.0f;
    float c00 = 0.0f, c01 = f21 * (1.0f/6.0f), c10 = 0.0f, c11 = 0.0f;
    float l00 = fmaf(f22, 1.0f/6.0f, 1.0f);
    float l10 = f32 * (1.0f/6.0f);
    float l11 = fmaf(f33, 1.0f/6.0f, 1.0f);
#pragma unroll
    for (int m = 5; m >= 1; --m) {
        const float rm = 1.0f / (float)m;  // folds to literal under unroll
        const float p00 = f00*t00 + f01*t10;
        const float p01 = f00*t01 + f01*t11;
        const float p10 = f10*t00;
        const float p11 = f10*t01;
        const float q00 = f21*t10 + f22*c00;
        const float q01 = f21*t11 + f22*c01;
        const float q10 = f32*c00 + f33*c10;
        const float q11 = f32*c01 + f33*c11;
        const float m00 = f22*l00;
        const float m10 = f32*l00 + f33*l10;
        const float m11 = f33*l11;
        t00 = fmaf(p00, rm, 1.0f); t01 = p01*rm;
        t10 = p10*rm;              t11 = fmaf(p11, rm, 1.0f);
        c00 = q00*rm; c01 = q01*rm; c10 = q10*rm; c11 = q11*rm;
        l00 = fmaf(m00, rm, 1.0f); l10 = m10*rm; l11 = fmaf(m11, rm, 1.0f);
    }

    // 4 squarings — matrix only
#pragma unroll
    for (int i = 0; i < NSQ; ++i) {
        const float p00 = t00*t00 + t01*t10;
        const float p01 = t00*t01 + t01*t11;
        const float p10 = t10*t00 + t11*t10;
        const float p11 = t10*t01 + t11*t11;
        const float q00 = c00*t00 + c01*t10 + l00*c00;
        const float q01 = c00*t01 + c01*t11 + l00*c01;
        const float q10 = c10*t00 + c11*t10 + l10*c00 + l11*c10;
        const float q11 = c10*t01 + c11*t11 + l10*c01 + l11*c11;
        const float m00 = l00*l00;
        const float m10 = l10*l00 + l11*l10;
        const float m11 = l11*l11;
        t00 = p00; t01 = p01; t10 = p10; t11 = p11;
        c00 = q00; c01 = q01; c10 = q10; c11 = q11;
        l00 = m00; l10 = m10; l11 = m11;
    }

    // phi1/phi2 via exact back-substitution solves (balanced space)
    const float aw  = a * iw;           // a/w
    const float rdt = frcp(dt);
    const float rF  = iw * rdt;         // 1/(w dt)
    const float rS  = rwsf * rdt;       // 1/(wsf dt)
    const float rD  = rwdf * rdt;       // 1/(wdf dt)
    const float wS  = w * rwsf;         // w/wsf
    const float wD  = w * rwdf;         // w/wdf
    const float g0u = w * dt;

    // G1 = M^{-1}(E-I)g  (balanced)
    const float y0 = t10;
    const float y1 = -fmaf(aw, t10, t00 - 1.0f);
    const float y2 = fmaf(-wS, c00, y1);
    const float y3 = fmaf(-wD, c10, y2);
    // G2 = M^{-1}(G1 - g)  (balanced)
    const float s0 = y0 - g0u;
    const float z0 = y1 * rF;
    const float z1 = -fmaf(aw, z0, rF * s0);
    const float z2 = fmaf(-y2, rS, z1);
    const float z3 = fmaf(-y3, rD, z2);

    // unbalance: Ad = D E D^-1, D = diag(w,1,1,1); G *= D
    Aff r;
    r.a00 = t00;      r.a01 = w * t01;
    r.a10 = t10 * iw; r.a11 = t11;
    r.a20 = c00 * iw; r.a21 = c01; r.a22 = l00;
    r.a30 = c10 * iw; r.a31 = c11; r.a32 = l10; r.a33 = l11;
    const float G10 = w * y0, G20 = w * z0;
    // c = G1*uk + G2*(uk1-uk)   (== Bd*uk + Bt*uk1)
    const float du = uk1 - uk;
    r.c0 = fmaf(G10, uk, G20 * du);
    r.c1 = fmaf(y1,  uk, z1 * du);
    r.c2 = fmaf(y2,  uk, z2 * du);
    r.c3 = fmaf(y3,  uk, z3 * du);
    return r;
}

__global__ __launch_bounds__(TPB) void pbw_kernel(
    const float* __restrict__ it_eff,
    const float* __restrict__ ts,
    const float* __restrict__ p_tin_prod,
    const float* __restrict__ p_tmil_raw,
    const float* __restrict__ p_aamp_raw,
    const float* __restrict__ p_aloop_raw,
    const float* __restrict__ p_tout_raw,
    const float* __restrict__ p_tsf_raw,
    const float* __restrict__ p_tdiff_raw,
    float* __restrict__ out)
{
    __shared__ float swcA[6];       // wave-0 oscillator composite
    __shared__ float swcB[5];       // wave-0 low composite
    __shared__ float sy[SS + 4];    // output staging (+4 pad for tail thread)

    const int b = blockIdx.x;
    const int t = threadIdx.x;
    const int lane = t & 63;
    const int wv = t >> 6;

    // derived scalar params (wave-uniform)
    const float tin_prod  = p_tin_prod[0];
    const float tmil_prod = log1pf(expf(p_tmil_raw[0]));
    const float Aamp1     = 1.0f / log1pf(expf(p_aamp_raw[0])) + 1.0f;
    const float Aloop1    = 1.0f / log1pf(expf(p_aloop_raw[0])) + 1.0f;
    const float tau_out   = log1pf(expf(p_tout_raw[0]));
    const float sp_sf     = log1pf(expf(p_tsf_raw[0]));
    const float sp_df     = log1pf(expf(p_tdiff_raw[0]));
    const float wsf       = 1.0f / sp_sf;
    const float wdf       = 1.0f / sp_df;
    const float sprod = tin_prod + tmil_prod;             // (tin+tml)*I
    const float aprod = fmaf(Aamp1, tmil_prod, tin_prod); // (tin+Aamp1*tml)*I

    const float* rowI = it_eff + (size_t)b * SS;
    const float* rowT = ts     + (size_t)b * SS;

    // thread t owns steps k = 4t .. 4t+3 (last thread: 3 real + identity)
    const int k0 = 4 * t;
    const float4 I4 = *(const float4*)(rowI + k0);
    const float4 T4 = *(const float4*)(rowT + k0);
    const bool last = (t == TPB - 1);
    const float I_4 = last ? 1.0f : rowI[k0 + 4];
    const float T_4 = last ? (T4.w + 1e-4f) : rowT[k0 + 4];

    const float u_0 = flog(I4.x);
    const float u_1 = flog(I4.y);
    const float u_2 = flog(I4.z);
    const float u_3 = flog(I4.w);
    const float u_4 = flog(I_4);
    const float u0  = flog(rowI[0]);   // broadcast load

    Aff m0 = make_step(I4.y, T4.y - T4.x, u_0, u_1,
                       sprod, aprod, tau_out, Aloop1, wsf, wdf, sp_sf, sp_df);
    Aff m1 = make_step(I4.z, T4.z - T4.y, u_1, u_2,
                       sprod, aprod, tau_out, Aloop1, wsf, wdf, sp_sf, sp_df);
    Aff m2 = make_step(I4.w, T4.w - T4.z, u_2, u_3,
                       sprod, aprod, tau_out, Aloop1, wsf, wdf, sp_sf, sp_df);
    Aff m3 = make_step(I_4, T_4 - T4.w, u_3, u_4,
                       sprod, aprod, tau_out, Aloop1, wsf, wdf, sp_sf, sp_df);
    if (last) m3 = aff_identity();

    // ================= Phase A: oscillator (x0,x1) scan =================
    const Osc s0 = {m0.a00, m0.a01, m0.a10, m0.a11, m0.c0, m0.c1};
    const Osc s1 = {m1.a00, m1.a01, m1.a10, m1.a11, m1.c0, m1.c1};
    const Osc s2 = {m2.a00, m2.a01, m2.a10, m2.a11, m2.c0, m2.c1};
    const Osc s3 = {m3.a00, m3.a01, m3.a10, m3.a11, m3.c0, m3.c1};

    Osc oc = osc_compose(osc_compose(s3, s2), osc_compose(s1, s0));
#pragma unroll
    for (int d = 1; d < 64; d <<= 1) {
        Osc p = osc_shfl_up(oc, d);
        p = osc_sel(p, lane >= d);
        oc = osc_compose(oc, p);
    }
    if (wv == 0 && lane == 63) {
        swcA[0]=oc.a00; swcA[1]=oc.a01; swcA[2]=oc.a10; swcA[3]=oc.a11;
        swcA[4]=oc.c0;  swcA[5]=oc.c1;
    }
    __syncthreads();

    float v0 = 0.0f, v1 = u0;
    if (wv == 1) {
        Osc wm = {swcA[0], swcA[1], swcA[2], swcA[3], swcA[4], swcA[5]};
        osc_apply(wm, v0, v1);
    }
    Osc oex = osc_shfl_up(oc, 1);
    oex = osc_sel(oex, lane >= 1);
    osc_apply(oex, v0, v1);

    // v at the 4 local step-starts
    const float va0 = v0, vb0 = v1;
    osc_apply(s0, v0, v1); const float va1 = v0, vb1 = v1;
    osc_apply(s1, v0, v1); const float va2 = v0, vb2 = v1;
    osc_apply(s2, v0, v1); const float va3 = v0, vb3 = v1;

    // ================= Phase B: lower-tri (x2,x3) scan =================
    const Low b0 = {m0.a22, m0.a32, m0.a33,
                    m0.a20*va0 + m0.a21*vb0 + m0.c2,
                    m0.a30*va0 + m0.a31*vb0 + m0.c3};
    const Low b1 = {m1.a22, m1.a32, m1.a33,
                    m1.a20*va1 + m1.a21*vb1 + m1.c2,
                    m1.a30*va1 + m1.a31*vb1 + m1.c3};
    const Low b2 = {m2.a22, m2.a32, m2.a33,
                    m2.a20*va2 + m2.a21*vb2 + m2.c2,
                    m2.a30*va2 + m2.a31*vb2 + m2.c3};
    const Low b3 = {m3.a22, m3.a32, m3.a33,
                    m3.a20*va3 + m3.a21*vb3 + m3.c2,
                    m3.a30*va3 + m3.a31*vb3 + m3.c3};

    Low lc = low_compose(low_compose(b3, b2), low_compose(b1, b0));
#pragma unroll
    for (int d = 1; d < 64; d <<= 1) {
        Low p = low_shfl_up(lc, d);
        p = low_sel(p, lane >= d);
        lc = low_compose(lc, p);
    }
    if (wv == 0 && lane == 63) {
        swcB[0]=lc.l00; swcB[1]=lc.l10; swcB[2]=lc.l11;
        swcB[3]=lc.c0;  swcB[4]=lc.c1;
    }
    __syncthreads();

    float x2 = u0, x3 = u0;
    if (wv == 1) {
        Low wm = {swcB[0], swcB[1], swcB[2], swcB[3], swcB[4]};
        low_apply(wm, x2, x3);
    }
    Low lex = low_shfl_up(lc, 1);
    lex = low_sel(lex, lane >= 1);
    low_apply(lex, x2, x3);

    // replay: y = x3 after each local step
    low_apply(b0, x2, x3); sy[k0 + 1] = x3;
    low_apply(b1, x2, x3); sy[k0 + 2] = x3;
    low_apply(b2, x2, x3); sy[k0 + 3] = x3;
    low_apply(b3, x2, x3); sy[k0 + 4] = x3;   // k0+4==512 lands in pad
    if (t == 0) sy[0] = u0;

    __syncthreads();

    // coalesced float4 store
    float4* po = (float4*)(out + (size_t)b * SS);
    po[t] = *(const float4*)&sy[4 * t];
}

extern "C" void kernel_launch(void* const* d_in, const int* in_sizes, int n_in,
                              void* d_out, int out_size, void* d_ws, size_t ws_size,
                              hipStream_t stream) {
    const float* it_eff = (const float*)d_in[0];
    const float* ts     = (const float*)d_in[1];
    const float* p2 = (const float*)d_in[2];
    const float* p3 = (const float*)d_in[3];
    const float* p4 = (const float*)d_in[4];
    const float* p5 = (const float*)d_in[5];
    const float* p6 = (const float*)d_in[6];
    const float* p7 = (const float*)d_in[7];
    const float* p8 = (const float*)d_in[8];
    float* out = (float*)d_out;

    pbw_kernel<<<dim3(BB), dim3(TPB), 0, stream>>>(
        it_eff, ts, p2, p3, p4, p5, p6, p7, p8, out);
}